// Round 12
// baseline (579.559 us; speedup 1.0000x reference)
//
#include <hip/hip_runtime.h>
#include <math.h>

#define D 128
#define NF 10
#define N_IP 20000
#define N_CONN 100000
#define NE 200000
#define T_ROUNDS 3

typedef unsigned short u16;
using bf16x8 = __attribute__((ext_vector_type(8))) short;
using floatx4 = __attribute__((ext_vector_type(4))) float;

__device__ inline u16 f2bf(float f) {
  union { float f; unsigned u; } v; v.f = f;
  unsigned u = v.u;
  return (u16)((u + 0x7fffu + ((u >> 16) & 1u)) >> 16);  // RNE
}
__device__ inline float bf2f(u16 h) {
  union { unsigned u; float f; } v; v.u = ((unsigned)h) << 16; return v.f;
}

__device__ inline float fsigmoid(float s) { return 1.f / (1.f + __expf(-s)); }
__device__ inline float ftanh(float a) {
  a = fminf(fmaxf(a, -15.f), 15.f);
  float e = __expf(2.f * a);
  return (e - 1.f) / (e + 1.f);
}

// ---------------- fused init: states + cnt zero ----------------
__global__ void k_init_all(u16* __restrict__ ip_state, u16* __restrict__ conn_state,
                           const float* __restrict__ feat, int* __restrict__ cnt) {
  int i = blockIdx.x * blockDim.x + threadIdx.x;
  const int nip = N_IP * D;
  const int nstate = (N_IP + N_CONN) * D;
  if (i < nip) {
    ip_state[i] = 0x3F80;  // bf16(1.0)
  } else if (i < nstate) {
    int j = i - nip;
    int r = j >> 7, c = j & 127;
    conn_state[j] = (c < NF) ? f2bf(feat[r * NF + c]) : (u16)0;
  }
  if (i < N_CONN + N_IP) cnt[i] = 0;
}

// ---------------- fused weight prep (all matrices, bf16 [col][k]) ----------------
__global__ void k_prep_all(
    const float* __restrict__ gik, const float* __restrict__ gir,
    const float* __restrict__ gck, const float* __restrict__ gcr,
    const float* __restrict__ Wm1, const float* __restrict__ Wm2,
    const float* __restrict__ Wr1, const float* __restrict__ Wr2,
    u16* __restrict__ gikb, u16* __restrict__ girb,
    u16* __restrict__ gckb, u16* __restrict__ gcrb,
    u16* __restrict__ wm1b, u16* __restrict__ wm2b,
    u16* __restrict__ wm1t, u16* __restrict__ wm2t,
    u16* __restrict__ wr1b, u16* __restrict__ wr2b) {
  int i = blockIdx.x * blockDim.x + threadIdx.x;
  if (i < 196608) {  // 4 GRU mats (128x384 -> [col][k] 384x128)
    int m = i / 49152, r = i % 49152;
    const float* W = (m == 0) ? gik : (m == 1) ? gir : (m == 2) ? gck : gcr;
    u16* Wb = (m == 0) ? gikb : (m == 1) ? girb : (m == 2) ? gckb : gcrb;
    int col = r >> 7, k = r & 127;
    Wb[r] = f2bf(W[k * 384 + col]);
  } else if (i < 278528) {  // 5 x 128x128 blocks
    int j = i - 196608;
    int m = j / 16384, r = j % 16384;
    const float* W; u16* Wb; int k0;
    if (m == 0) { W = Wm1; Wb = wm1b; k0 = 128; }
    else if (m == 1) { W = Wm2; Wb = wm2b; k0 = 128; }
    else if (m == 2) { W = Wm1; Wb = wm1t; k0 = 0; }
    else if (m == 3) { W = Wm2; Wb = wm2t; k0 = 0; }
    else { W = Wr1; Wb = wr1b; k0 = 0; }
    int col = r >> 7, k = r & 127;
    Wb[r] = f2bf(W[(k0 + k) * 128 + col]);
  } else if (i < 286720) {  // Wr2 128x64 -> [col][k] 64x128
    int r = i - 278528;
    int col = r >> 7, k = r & 127;
    wr2b[r] = f2bf(Wr2[k * 64 + col]);
  }
}

__global__ void k_count(const int* __restrict__ d1, const int* __restrict__ d2,
                        int* __restrict__ c1, int* __restrict__ c2) {
  int e = blockIdx.x * blockDim.x + threadIdx.x;
  if (e >= NE) return;
  atomicAdd(&c1[d1[e]], 1);
  atomicAdd(&c2[d2[e]], 1);
}

// ---------------- merged 3-pass exclusive scan (both segment arrays) ----------------
__global__ void k_scan_part2(const int* __restrict__ cnt1, int* __restrict__ bsum1,
                             int n1, int nb1,
                             const int* __restrict__ cnt2, int* __restrict__ bsum2, int n2) {
  const int* cnt; int* bsum; int n, b;
  if ((int)blockIdx.x < nb1) { cnt = cnt1; bsum = bsum1; n = n1; b = blockIdx.x; }
  else { cnt = cnt2; bsum = bsum2; n = n2; b = blockIdx.x - nb1; }
  int t = threadIdx.x;
  int base = b * 1024 + t * 4;
  int s = 0;
#pragma unroll
  for (int i = 0; i < 4; i++) { int j = base + i; if (j < n) s += cnt[j]; }
  for (int d = 32; d > 0; d >>= 1) s += __shfl_xor(s, d, 64);
  __shared__ int wred[4];
  int lane = t & 63, wv = t >> 6;
  if (lane == 0) wred[wv] = s;
  __syncthreads();
  if (t == 0) bsum[b] = wred[0] + wred[1] + wred[2] + wred[3];
}

__device__ inline void scan_mid_body(int* bsum, int m, int t) {
  int v = (t < m) ? bsum[t] : 0;
  int lane = t & 63, wv = t >> 6;
  int x = v;
  for (int d = 1; d < 64; d <<= 1) { int y = __shfl_up(x, d, 64); if (lane >= d) x += y; }
  __shared__ int wsum[4];
  if (lane == 63) wsum[wv] = x;
  __syncthreads();
  int add = 0;
  for (int i = 0; i < wv; i++) add += wsum[i];
  int ex = add + x - v;
  if (t < m) bsum[t] = ex;
  __syncthreads();
}

__global__ void k_scan_mid2(int* __restrict__ bsum1, int m1, int* __restrict__ bsum2, int m2) {
  int t = threadIdx.x;
  scan_mid_body(bsum1, m1, t);
  scan_mid_body(bsum2, m2, t);
}

// pass 3: write off AND cur
__global__ void k_scan_final2(const int* __restrict__ cnt1, const int* __restrict__ bsum1,
                              int* __restrict__ off1, int* __restrict__ cur1, int n1, int nb1,
                              const int* __restrict__ cnt2, const int* __restrict__ bsum2,
                              int* __restrict__ off2, int* __restrict__ cur2, int n2) {
  const int* cnt; const int* bsum; int* off; int* cur; int n, b;
  if ((int)blockIdx.x < nb1) {
    cnt = cnt1; bsum = bsum1; off = off1; cur = cur1; n = n1; b = blockIdx.x;
  } else {
    cnt = cnt2; bsum = bsum2; off = off2; cur = cur2; n = n2; b = blockIdx.x - nb1;
  }
  int t = threadIdx.x;
  int base = b * 1024 + t * 4;
  int vals[4]; int s = 0;
#pragma unroll
  for (int i = 0; i < 4; i++) {
    int j = base + i;
    vals[i] = (j < n) ? cnt[j] : 0;
    s += vals[i];
  }
  int lane = t & 63, wv = t >> 6;
  int x = s;
  for (int d = 1; d < 64; d <<= 1) { int y = __shfl_up(x, d, 64); if (lane >= d) x += y; }
  __shared__ int wsum[4];
  if (lane == 63) wsum[wv] = x;
  __syncthreads();
  int add = 0;
  for (int i = 0; i < wv; i++) add += wsum[i];
  int run = add + x - s + bsum[b];
#pragma unroll
  for (int i = 0; i < 4; i++) {
    int j = base + i;
    if (j < n) { off[j] = run; cur[j] = run; }
    run += vals[i];
  }
}

__global__ void k_scatter(const int* __restrict__ s1, const int* __restrict__ d1,
                          const int* __restrict__ s2, const int* __restrict__ d2,
                          int* __restrict__ cur1, int* __restrict__ cur2,
                          int* __restrict__ o1, int* __restrict__ o2) {
  int e = blockIdx.x * blockDim.x + threadIdx.x;
  if (e >= NE) return;
  int p1 = atomicAdd(&cur1[d1[e]], 1);
  o1[p1] = s1[e];
  int p2 = atomicAdd(&cur2[d2[e]], 1);
  o2[p2] = s2[e];
}

// ---------------- merged P-GEMM (bf16 in/out): P = S @ Wt^T (prologue, round 0) ----------------
__global__ __launch_bounds__(256) void k_gemmP(
    const u16* __restrict__ S1, const u16* __restrict__ Wt1, u16* __restrict__ P1,
    int M1, int tiles1,
    const u16* __restrict__ S2, const u16* __restrict__ Wt2, u16* __restrict__ P2,
    int M2) {
  __shared__ __align__(16) u16 Wls[128 * 128];  // 32KB; reused as C (64x136)
  const u16* S; const u16* Wt; u16* P; int M, bm;
  if ((int)blockIdx.x < tiles1) { S = S1; Wt = Wt1; P = P1; M = M1; bm = blockIdx.x * 64; }
  else { S = S2; Wt = Wt2; P = P2; M = M2; bm = (blockIdx.x - tiles1) * 64; }
  const int tid = threadIdx.x, wv = tid >> 6, lane = tid & 63;
  const int lrow = lane & 15, quad = lane >> 4;
#pragma unroll
  for (int i = 0; i < 8; i++) {  // stage W swizzled
    int task = i * 256 + tid;
    int col = task >> 4, gr = task & 15;
    uint4 v = *(const uint4*)(Wt + (size_t)col * 128 + gr * 8);
    *(uint4*)(Wls + (size_t)col * 128 + ((gr ^ (col & 15)) * 8)) = v;
  }
  const int arow = bm + wv * 16 + lrow;
  const bool arv = arow < M;
  const bf16x8 zv = {0, 0, 0, 0, 0, 0, 0, 0};
  bf16x8 a[4];
#pragma unroll
  for (int ks = 0; ks < 4; ks++)
    a[ks] = arv ? *(const bf16x8*)(S + (size_t)arow * 128 + quad * 8 + ks * 32) : zv;
  __syncthreads();
  floatx4 acc[8];
#pragma unroll
  for (int ct = 0; ct < 8; ct++) acc[ct] = {0.f, 0.f, 0.f, 0.f};
#pragma unroll
  for (int ks = 0; ks < 4; ks++) {
#pragma unroll
    for (int ct = 0; ct < 8; ct++) {
      int col = ct * 16 + lrow;
      bf16x8 b = *(const bf16x8*)(Wls + (size_t)col * 128 + (((4 * ks + quad) ^ lrow) * 8));
      acc[ct] = __builtin_amdgcn_mfma_f32_16x16x32_bf16(a[ks], b, acc[ct], 0, 0, 0);
    }
  }
  __syncthreads();  // W reads done; reuse as C
  u16* Cls = Wls;   // 64 x 136
#pragma unroll
  for (int ct = 0; ct < 8; ct++) {
    int col = ct * 16 + lrow;
#pragma unroll
    for (int reg = 0; reg < 4; reg++) {
      int lr = wv * 16 + quad * 4 + reg;
      Cls[(size_t)lr * 136 + col] = f2bf(acc[ct][reg]);
    }
  }
  __syncthreads();
#pragma unroll
  for (int i = 0; i < 4; i++) {  // coalesced bf16 write-out
    int task = i * 256 + tid;
    int row = task >> 4, c8 = task & 15;
    int gr2 = bm + row;
    if (gr2 < M)
      *(uint4*)(P + (size_t)gr2 * 128 + c8 * 8) = *(const uint4*)(Cls + (size_t)row * 136 + c8 * 8);
  }
}

// ---------------- fused message+GRU+P_next: per 64-node block ----------------
// Q-GEMM + gather-mean + GRU (as round 11), then tail: P_next = new_state @ Wt^T
// (stages Wt over the dead Wg region, A-frags from Hls new state). P is
// double-buffered at the host level: read Pg (frozen), write Pout.
__global__ __launch_bounds__(256, 2) void k_msggru(
    u16* __restrict__ st1, const u16* __restrict__ wq1, const float* __restrict__ qb1,
    const u16* __restrict__ P1g, const int* __restrict__ srcs1g,
    const int* __restrict__ off1g, const int* __restrict__ cnt1g,
    const u16* __restrict__ wx1, const u16* __restrict__ wh1, const float* __restrict__ gb1,
    const u16* __restrict__ wt1, u16* __restrict__ Pout1, int r1, int tiles1,
    u16* __restrict__ st2, const u16* __restrict__ wq2, const float* __restrict__ qb2,
    const u16* __restrict__ P2g, const int* __restrict__ srcs2g,
    const int* __restrict__ off2g, const int* __restrict__ cnt2g,
    const u16* __restrict__ wx2, const u16* __restrict__ wh2, const float* __restrict__ gb2,
    const u16* __restrict__ wt2, u16* __restrict__ Pout2, int r2) {
  __shared__ __align__(16) char smem[49152];
  u16* Wq = (u16*)smem;                    // phase A: 128x128 bf16 swizzled (32KB); also Wt in tail
  u16* Qb = (u16*)smem;                    // phase B: 64x128 bf16 (16KB)
  u16* Xb = (u16*)(smem + 16384);          // phase B: 64x128 bf16 swizzled (16KB)
  u16* Wg = (u16*)smem;                    // phase C: 6x16x128 bf16 swizzled (24KB)
  u16* Hls = (u16*)(smem + 32768);         // 64x128 bf16 swizzled (16KB)
  u16* H; const u16* Wqb; const float* qbias; const u16* P;
  const int* srcs; const int* off; const int* cnt;
  const u16* Wxb; const u16* Whb; const float* gbias;
  const u16* Wt; u16* Pout; int rows, bm;
  if ((int)blockIdx.x < tiles1) {
    H = st1; Wqb = wq1; qbias = qb1; P = P1g; srcs = srcs1g; off = off1g; cnt = cnt1g;
    Wxb = wx1; Whb = wh1; gbias = gb1; Wt = wt1; Pout = Pout1; rows = r1;
    bm = blockIdx.x * 64;
  } else {
    H = st2; Wqb = wq2; qbias = qb2; P = P2g; srcs = srcs2g; off = off2g; cnt = cnt2g;
    Wxb = wx2; Whb = wh2; gbias = gb2; Wt = wt2; Pout = Pout2; rows = r2;
    bm = (blockIdx.x - tiles1) * 64;
  }
  const int tid = threadIdx.x, wv = tid >> 6, lane = tid & 63;
  const int lrow = lane & 15, quad = lane >> 4;
  const uint4 z4 = {0, 0, 0, 0};
  // --- phase A: stage Wq (swizzled) + H (swizzled) ---
#pragma unroll
  for (int i = 0; i < 8; i++) {
    int task = i * 256 + tid;
    int col = task >> 4, gr = task & 15;
    uint4 v = *(const uint4*)(Wqb + (size_t)col * 128 + gr * 8);
    *(uint4*)(Wq + (size_t)col * 128 + ((gr ^ (col & 15)) * 8)) = v;
  }
#pragma unroll
  for (int i = 0; i < 4; i++) {
    int task = i * 256 + tid;
    int row = task >> 4, g = task & 15;
    int grow = bm + row;
    uint4 v = (grow < rows) ? *(const uint4*)(H + (size_t)grow * 128 + g * 8) : z4;
    *(uint4*)(Hls + (size_t)row * 128 + ((g ^ (row & 15)) * 8)) = v;
  }
  __syncthreads();
  // state A-frags (serve Q-GEMM and GRU h-GEMM)
  bf16x8 ah[4];
#pragma unroll
  for (int ks = 0; ks < 4; ks++)
    ah[ks] = *(const bf16x8*)(Hls + (size_t)(wv * 16 + lrow) * 128 + (((ks * 4 + quad) ^ lrow) * 8));
  // --- Q-GEMM: Q = state @ Wq^T ---
  floatx4 acc[8];
#pragma unroll
  for (int ct = 0; ct < 8; ct++) acc[ct] = {0.f, 0.f, 0.f, 0.f};
#pragma unroll
  for (int ks = 0; ks < 4; ks++) {
#pragma unroll
    for (int ct = 0; ct < 8; ct++) {
      int col = ct * 16 + lrow;
      bf16x8 b = *(const bf16x8*)(Wq + (size_t)col * 128 + (((4 * ks + quad) ^ lrow) * 8));
      acc[ct] = __builtin_amdgcn_mfma_f32_16x16x32_bf16(ah[ks], b, acc[ct], 0, 0, 0);
    }
  }
  __syncthreads();  // Wq reads done; region0 becomes Qb/Xb
  // --- write Q (+bias) as bf16, plain [row][col] ---
#pragma unroll
  for (int ct = 0; ct < 8; ct++) {
    int col = ct * 16 + lrow;
    float bv = qbias[col];
#pragma unroll
    for (int reg = 0; reg < 4; reg++) {
      int lr = wv * 16 + quad * 4 + reg;
      Qb[(size_t)lr * 128 + col] = f2bf(acc[ct][reg] + bv);
    }
  }
  __syncthreads();
  // --- gather-mean: X[node] = mean_e relu(P[src_e] + Q[node]) -> Xb (swizzled) ---
#pragma unroll
  for (int it = 0; it < 4; it++) {
    int task = it * 256 + tid;
    int nl = task >> 4, g = task & 15;
    int node = bm + nl;
    if (node >= rows) continue;
    int c8 = g << 3;
    float q[8];
    {
      uint4 qv = *(const uint4*)(Qb + (size_t)nl * 128 + c8);
      unsigned qq[4] = {qv.x, qv.y, qv.z, qv.w};
#pragma unroll
      for (int k = 0; k < 4; k++) {
        q[2 * k] = __uint_as_float(qq[k] << 16);
        q[2 * k + 1] = __uint_as_float(qq[k] & 0xffff0000u);
      }
    }
    float acg[8] = {0.f, 0.f, 0.f, 0.f, 0.f, 0.f, 0.f, 0.f};
    int o = off[node], n = cnt[node];
    int i = 0;
    for (; i + 4 <= n; i += 4) {
      int s0 = srcs[o + i], s1 = srcs[o + i + 1], s2 = srcs[o + i + 2], s3 = srcs[o + i + 3];
      uint4 v0 = *(const uint4*)(P + (size_t)s0 * 128 + c8);
      uint4 v1 = *(const uint4*)(P + (size_t)s1 * 128 + c8);
      uint4 v2 = *(const uint4*)(P + (size_t)s2 * 128 + c8);
      uint4 v3 = *(const uint4*)(P + (size_t)s3 * 128 + c8);
      unsigned w[16] = {v0.x, v0.y, v0.z, v0.w, v1.x, v1.y, v1.z, v1.w,
                        v2.x, v2.y, v2.z, v2.w, v3.x, v3.y, v3.z, v3.w};
#pragma unroll
      for (int e = 0; e < 4; e++)
#pragma unroll
        for (int k = 0; k < 4; k++) {
          unsigned ww = w[e * 4 + k];
          float lo = __uint_as_float(ww << 16);
          float hi = __uint_as_float(ww & 0xffff0000u);
          acg[2 * k] += fmaxf(lo + q[2 * k], 0.f);
          acg[2 * k + 1] += fmaxf(hi + q[2 * k + 1], 0.f);
        }
    }
    for (; i < n; i++) {
      int s0 = srcs[o + i];
      uint4 v0 = *(const uint4*)(P + (size_t)s0 * 128 + c8);
      unsigned w[4] = {v0.x, v0.y, v0.z, v0.w};
#pragma unroll
      for (int k = 0; k < 4; k++) {
        unsigned ww = w[k];
        float lo = __uint_as_float(ww << 16);
        float hi = __uint_as_float(ww & 0xffff0000u);
        acg[2 * k] += fmaxf(lo + q[2 * k], 0.f);
        acg[2 * k + 1] += fmaxf(hi + q[2 * k + 1], 0.f);
      }
    }
    float inv = 1.f / fmaxf((float)n, 1.f);
    bf16x8 ov;
#pragma unroll
    for (int k = 0; k < 8; k++) ov[k] = (short)f2bf(acg[k] * inv);
    *(bf16x8*)(Xb + (size_t)nl * 128 + ((g ^ (nl & 15)) * 8)) = ov;
  }
  __syncthreads();
  // --- x A-frags from Xb ---
  bf16x8 ax[4];
#pragma unroll
  for (int ks = 0; ks < 4; ks++)
    ax[ks] = *(const bf16x8*)(Xb + (size_t)(wv * 16 + lrow) * 128 + (((ks * 4 + quad) ^ lrow) * 8));
  const int lr0 = wv * 16 + quad * 4;
  // --- GRU chunk loop (Wg overlays dead Qb/Xb) ---
  for (int ch = 0; ch < 8; ch++) {
    __syncthreads();  // ch=0: ax/Qb reads done; ch>0: prev Wg reads done
#pragma unroll
    for (int p = 0; p < 2; p++) {
      uint4 v[3];
#pragma unroll
      for (int j = 0; j < 3; j++) {
        int task = (p * 3 + j) * 256 + tid;
        int seg = task >> 8, rem = task & 255;
        int col = rem >> 4, gr = rem & 15;
        const u16* gsrc = (seg < 3 ? Wxb : Whb) +
                          (size_t)((seg < 3 ? seg : seg - 3) * 128 + ch * 16 + col) * 128 + gr * 8;
        v[j] = *(const uint4*)gsrc;
      }
#pragma unroll
      for (int j = 0; j < 3; j++) {
        int task = (p * 3 + j) * 256 + tid;
        int seg = task >> 8, rem = task & 255;
        int col = rem >> 4, gr = rem & 15;
        *(uint4*)(Wg + (size_t)(seg * 16 + col) * 128 + ((gr ^ col) * 8)) = v[j];
      }
    }
    __syncthreads();
    floatx4 gacc[3][2];
#pragma unroll
    for (int g = 0; g < 3; g++) {
      gacc[g][0] = {0.f, 0.f, 0.f, 0.f};
      gacc[g][1] = {0.f, 0.f, 0.f, 0.f};
    }
#pragma unroll
    for (int ks = 0; ks < 4; ks++) {
      int posu = ((4 * ks + quad) ^ lrow) * 8;
#pragma unroll
      for (int g = 0; g < 3; g++) {
        bf16x8 bx = *(const bf16x8*)(Wg + (size_t)(g * 16 + lrow) * 128 + posu);
        bf16x8 bh = *(const bf16x8*)(Wg + (size_t)((3 + g) * 16 + lrow) * 128 + posu);
        gacc[g][0] = __builtin_amdgcn_mfma_f32_16x16x32_bf16(ax[ks], bx, gacc[g][0], 0, 0, 0);
        gacc[g][1] = __builtin_amdgcn_mfma_f32_16x16x32_bf16(ah[ks], bh, gacc[g][1], 0, 0, 0);
      }
    }
    int hcol = ch * 16 + lrow;
    float bxz = gbias[hcol];
    float bxr = gbias[128 + hcol];
    float bxh = gbias[256 + hcol];
    float bhz = gbias[384 + hcol];
    float bhr = gbias[384 + 128 + hcol];
    float bhh = gbias[384 + 256 + hcol];
    int ggr = 2 * ch + (lrow >> 3);
    int gel = lrow & 7;
#pragma unroll
    for (int reg = 0; reg < 4; reg++) {
      int lr = lr0 + reg;
      float xz = gacc[0][0][reg] + bxz;
      float xr = gacc[1][0][reg] + bxr;
      float xh = gacc[2][0][reg] + bxh;
      float hz = gacc[0][1][reg] + bhz;
      float hr = gacc[1][1][reg] + bhr;
      float hh = gacc[2][1][reg] + bhh;
      float z = fsigmoid(xz + hz);
      float rr = fsigmoid(xr + hr);
      float hc = ftanh(xh + rr * hh);
      u16* hp = Hls + (size_t)lr * 128 + ((ggr ^ (lr & 15)) * 8) + gel;
      float hold = bf2f(*hp);
      *hp = f2bf(z * hold + (1.f - z) * hc);
    }
  }
  __syncthreads();
  // --- write-out new state (coalesced) + stage Wt (overlays dead Wg/Wq region) ---
#pragma unroll
  for (int i = 0; i < 4; i++) {
    int task = i * 256 + tid;
    int row = task >> 4, g = task & 15;
    int grow = bm + row;
    if (grow < rows)
      *(uint4*)(H + (size_t)grow * 128 + g * 8) =
          *(const uint4*)(Hls + (size_t)row * 128 + ((g ^ (row & 15)) * 8));
  }
#pragma unroll
  for (int i = 0; i < 8; i++) {
    int task = i * 256 + tid;
    int col = task >> 4, gr = task & 15;
    uint4 v = *(const uint4*)(Wt + (size_t)col * 128 + gr * 8);
    *(uint4*)(Wq + (size_t)col * 128 + ((gr ^ (col & 15)) * 8)) = v;
  }
  // new-state A-frags from Hls (epilogue writes drained by the pre-write-out barrier)
  bf16x8 an[4];
#pragma unroll
  for (int ks = 0; ks < 4; ks++)
    an[ks] = *(const bf16x8*)(Hls + (size_t)(wv * 16 + lrow) * 128 + (((ks * 4 + quad) ^ lrow) * 8));
  __syncthreads();
  // --- P_next = new_state @ Wt^T ---
  floatx4 pacc[8];
#pragma unroll
  for (int ct = 0; ct < 8; ct++) pacc[ct] = {0.f, 0.f, 0.f, 0.f};
#pragma unroll
  for (int ks = 0; ks < 4; ks++) {
#pragma unroll
    for (int ct = 0; ct < 8; ct++) {
      int col = ct * 16 + lrow;
      bf16x8 b = *(const bf16x8*)(Wq + (size_t)col * 128 + (((4 * ks + quad) ^ lrow) * 8));
      pacc[ct] = __builtin_amdgcn_mfma_f32_16x16x32_bf16(an[ks], b, pacc[ct], 0, 0, 0);
    }
  }
  // C -> Hls (bf16, swizzled; Hls dead after the barrier above) then coalesced P write
#pragma unroll
  for (int ct = 0; ct < 8; ct++) {
    int col = ct * 16 + lrow;
    int g2 = col >> 3, el = col & 7;
#pragma unroll
    for (int reg = 0; reg < 4; reg++) {
      int lr = lr0 + reg;
      Hls[(size_t)lr * 128 + ((g2 ^ (lr & 15)) * 8) + el] = f2bf(pacc[ct][reg]);
    }
  }
  __syncthreads();
#pragma unroll
  for (int i = 0; i < 4; i++) {
    int task = i * 256 + tid;
    int row = task >> 4, g = task & 15;
    int grow = bm + row;
    if (grow < rows)
      *(uint4*)(Pout + (size_t)grow * 128 + g * 8) =
          *(const uint4*)(Hls + (size_t)row * 128 + ((g ^ (row & 15)) * 8));
  }
}

// ---------------- fully fused readout: 2 GEMMs + logits + softmax ----------------
__global__ __launch_bounds__(256) void k_readout2(
    const u16* __restrict__ S, const u16* __restrict__ W1b, const float* __restrict__ b1,
    const u16* __restrict__ W2b, const float* __restrict__ b2,
    const float* __restrict__ W3, const float* __restrict__ b3,
    float* __restrict__ out, int M) {
  __shared__ __align__(16) char smem[64 * 132 * 4];  // 33792 B
  u16* Wls = (u16*)smem;
  u16* H1ls = (u16*)smem;
  u16* W2ls = (u16*)(smem + 17408);
  u16* H2ls = (u16*)smem;
  float* W3ls = (float*)(smem + 9216);
  float* b3ls = (float*)(smem + 9216 + 3840);
  const int tid = threadIdx.x, wv = tid >> 6, lane = tid & 63;
  const int lrow = lane & 15, quad = lane >> 4;
  const int bm = blockIdx.x * 64;
#pragma unroll
  for (int i = 0; i < 8; i++) {
    int task = i * 256 + tid;
    int col = task >> 4, gr = task & 15;
    uint4 v = *(const uint4*)(W1b + (size_t)col * 128 + gr * 8);
    *(uint4*)(Wls + (size_t)col * 128 + ((gr ^ (col & 15)) * 8)) = v;
  }
  const int arow = bm + wv * 16 + lrow;
  const bool arv = arow < M;
  const bf16x8 zv = {0, 0, 0, 0, 0, 0, 0, 0};
  bf16x8 a[4];
#pragma unroll
  for (int ks = 0; ks < 4; ks++)
    a[ks] = arv ? *(const bf16x8*)(S + (size_t)arow * 128 + quad * 8 + ks * 32) : zv;
  __syncthreads();
  floatx4 acc1[8];
#pragma unroll
  for (int ct = 0; ct < 8; ct++) acc1[ct] = {0.f, 0.f, 0.f, 0.f};
#pragma unroll
  for (int ks = 0; ks < 4; ks++) {
#pragma unroll
    for (int ct = 0; ct < 8; ct++) {
      int col = ct * 16 + lrow;
      bf16x8 b = *(const bf16x8*)(Wls + (size_t)col * 128 + (((4 * ks + quad) ^ lrow) * 8));
      acc1[ct] = __builtin_amdgcn_mfma_f32_16x16x32_bf16(a[ks], b, acc1[ct], 0, 0, 0);
    }
  }
  __syncthreads();
#pragma unroll
  for (int ct = 0; ct < 8; ct++) {
    int col = ct * 16 + lrow;
    float bv = b1[col];
#pragma unroll
    for (int reg = 0; reg < 4; reg++) {
      int lr = wv * 16 + quad * 4 + reg;
      H1ls[(size_t)lr * 136 + col] = f2bf(fmaxf(acc1[ct][reg] + bv, 0.f));
    }
  }
#pragma unroll
  for (int i = 0; i < 4; i++) {
    int task = i * 256 + tid;
    int col = task >> 4, gr = task & 15;
    uint4 v = *(const uint4*)(W2b + (size_t)col * 128 + gr * 8);
    *(uint4*)(W2ls + (size_t)col * 128 + ((gr ^ (col & 15)) * 8)) = v;
  }
  __syncthreads();
  bf16x8 a2[4];
#pragma unroll
  for (int ks = 0; ks < 4; ks++)
    a2[ks] = *(const bf16x8*)(H1ls + (size_t)(wv * 16 + lrow) * 136 + quad * 8 + ks * 32);
  floatx4 acc2[4];
#pragma unroll
  for (int ct = 0; ct < 4; ct++) acc2[ct] = {0.f, 0.f, 0.f, 0.f};
#pragma unroll
  for (int ks = 0; ks < 4; ks++) {
#pragma unroll
    for (int ct = 0; ct < 4; ct++) {
      int col = ct * 16 + lrow;
      bf16x8 b = *(const bf16x8*)(W2ls + (size_t)col * 128 + (((4 * ks + quad) ^ lrow) * 8));
      acc2[ct] = __builtin_amdgcn_mfma_f32_16x16x32_bf16(a2[ks], b, acc2[ct], 0, 0, 0);
    }
  }
  __syncthreads();
#pragma unroll
  for (int ct = 0; ct < 4; ct++) {
    int col = ct * 16 + lrow;
    float bv = b2[col];
#pragma unroll
    for (int reg = 0; reg < 4; reg++) {
      int lr = wv * 16 + quad * 4 + reg;
      H2ls[(size_t)lr * 72 + col] = f2bf(fmaxf(acc2[ct][reg] + bv, 0.f));
    }
  }
  for (int l = tid; l < 960; l += 256) W3ls[l] = W3[l];
  if (tid < 15) b3ls[tid] = b3[tid];
  __syncthreads();
  if (tid < 64) {
    int row = tid, gr2 = bm + row;
    if (gr2 < M) {
      float lg[15];
#pragma unroll
      for (int c = 0; c < 15; c++) lg[c] = b3ls[c];
      for (int k = 0; k < 64; k++) {
        float hk = bf2f(H2ls[(size_t)row * 72 + k]);
#pragma unroll
        for (int c = 0; c < 15; c++) lg[c] += hk * W3ls[k * 15 + c];
      }
      float m = lg[0];
#pragma unroll
      for (int c = 1; c < 15; c++) m = fmaxf(m, lg[c]);
      float ssum = 0.f;
#pragma unroll
      for (int c = 0; c < 15; c++) { lg[c] = __expf(lg[c] - m); ssum += lg[c]; }
      float inv = 1.f / ssum;
#pragma unroll
      for (int c = 0; c < 15; c++) out[(size_t)gr2 * 15 + c] = lg[c] * inv;
    }
  }
}

// ---------------- launch ----------------
extern "C" void kernel_launch(void* const* d_in, const int* in_sizes, int n_in,
                              void* d_out, int out_size, void* d_ws, size_t ws_size,
                              hipStream_t stream) {
  const float* feat = (const float*)d_in[0];
  const int* src1 = (const int*)d_in[1];
  const int* dst1 = (const int*)d_in[2];
  const int* src2 = (const int*)d_in[3];
  const int* dst2 = (const int*)d_in[4];
  const float* Wm1 = (const float*)d_in[5];
  const float* bm1 = (const float*)d_in[6];
  const float* Wm2 = (const float*)d_in[7];
  const float* bm2 = (const float*)d_in[8];
  const float* gik = (const float*)d_in[9];
  const float* gir = (const float*)d_in[10];
  const float* gib = (const float*)d_in[11];
  const float* gck = (const float*)d_in[12];
  const float* gcr = (const float*)d_in[13];
  const float* gcb = (const float*)d_in[14];
  const float* Wr1 = (const float*)d_in[15];
  const float* br1 = (const float*)d_in[16];
  const float* Wr2 = (const float*)d_in[17];
  const float* br2 = (const float*)d_in[18];
  const float* Wr3 = (const float*)d_in[19];
  const float* br3 = (const float*)d_in[20];
  float* out = (float*)d_out;

  // ---- workspace layout (u16 units) ----
  u16* w16 = (u16*)d_ws;
  size_t o = 0;
  u16* ip_state = w16 + o;   o += (size_t)N_IP * D;
  u16* conn_state = w16 + o; o += (size_t)N_CONN * D;
  u16* P1a = w16 + o;        o += (size_t)N_IP * D;
  u16* P2a = w16 + o;        o += (size_t)N_CONN * D;
  u16* P1b = w16 + o;        o += (size_t)N_IP * D;
  u16* P2b = w16 + o;        o += (size_t)N_CONN * D;
  u16* gikb = w16 + o;       o += 49152;
  u16* girb = w16 + o;       o += 49152;
  u16* gckb = w16 + o;       o += 49152;
  u16* gcrb = w16 + o;       o += 49152;
  u16* wm1b = w16 + o;       o += 16384;
  u16* wm2b = w16 + o;       o += 16384;
  u16* wm1t = w16 + o;       o += 16384;
  u16* wm2t = w16 + o;       o += 16384;
  u16* wr1b = w16 + o;       o += 16384;
  u16* wr2b = w16 + o;       o += 8192;
  int* ip = (int*)(w16 + o);
  int* cnt1 = ip;  ip += N_CONN;
  int* cnt2 = ip;  ip += N_IP;
  int* off1 = ip;  ip += N_CONN;
  int* off2 = ip;  ip += N_IP;
  int* cur1 = ip;  ip += N_CONN;
  int* cur2 = ip;  ip += N_IP;
  int* srcs1 = ip; ip += NE;
  int* srcs2 = ip; ip += NE;
  int* bsum1 = ip; ip += 256;
  int* bsum2 = ip; ip += 256;

  const int BT = 256;

  // ---- fused init + weight prep ----
  const int nstate = (N_IP + N_CONN) * D;
  k_init_all<<<(nstate + BT - 1) / BT, BT, 0, stream>>>(ip_state, conn_state, feat, cnt1);
  k_prep_all<<<(286720 + BT - 1) / BT, BT, 0, stream>>>(
      gik, gir, gck, gcr, Wm1, Wm2, Wr1, Wr2,
      gikb, girb, gckb, gcrb, wm1b, wm2b, wm1t, wm2t, wr1b, wr2b);

  // ---- build CSR ----
  k_count<<<(NE + BT - 1) / BT, BT, 0, stream>>>(dst1, dst2, cnt1, cnt2);
  const int nb1 = (N_CONN + 1023) / 1024, nb2 = (N_IP + 1023) / 1024;
  k_scan_part2<<<nb1 + nb2, 256, 0, stream>>>(cnt1, bsum1, N_CONN, nb1, cnt2, bsum2, N_IP);
  k_scan_mid2<<<1, 256, 0, stream>>>(bsum1, nb1, bsum2, nb2);
  k_scan_final2<<<nb1 + nb2, 256, 0, stream>>>(cnt1, bsum1, off1, cur1, N_CONN, nb1,
                                               cnt2, bsum2, off2, cur2, N_IP);
  k_scatter<<<(NE + BT - 1) / BT, BT, 0, stream>>>(src1, dst1, src2, dst2,
                                                   cur1, cur2, srcs1, srcs2);

  const int t64ip = (N_IP + 63) / 64;       // 313
  const int t64cn = (N_CONN + 63) / 64;     // 1563

  // round-0 P from initial states
  k_gemmP<<<t64ip + t64cn, 256, 0, stream>>>(ip_state, wm1t, P1a, N_IP, t64ip,
                                             conn_state, wm2t, P2a, N_CONN);

  for (int t = 0; t < T_ROUNDS; t++) {
    u16* P1c = (t & 1) ? P1b : P1a;
    u16* P2c = (t & 1) ? P2b : P2a;
    u16* P1n = (t & 1) ? P1a : P1b;
    u16* P2n = (t & 1) ? P2a : P2b;
    // fused Q-GEMM + gather + GRU + next-round P for both node types.
    // conn side (reads ip P = P1c, produces conn P_next = P2n via wm2t);
    // ip side (reads conn P = P2c, produces ip P_next = P1n via wm1t).
    k_msggru<<<t64cn + t64ip, 256, 0, stream>>>(
        conn_state, wm1b, bm1, P1c, srcs1, off1, cnt1, gckb, gcrb, gcb,
        wm2t, P2n, N_CONN, t64cn,
        ip_state, wm2b, bm2, P2c, srcs2, off2, cnt2, gikb, girb, gib,
        wm1t, P1n, N_IP);
  }

  k_readout2<<<t64cn, 256, 0, stream>>>(conn_state, wr1b, br1, wr2b, br2,
                                        Wr3, br3, out, N_CONN);
}

// Round 13
// 515.986 us; speedup vs baseline: 1.1232x; 1.1232x over previous
//
#include <hip/hip_runtime.h>
#include <math.h>

#define D 128
#define NF 10
#define N_IP 20000
#define N_CONN 100000
#define NE 200000
#define T_ROUNDS 3

typedef unsigned short u16;
using bf16x8 = __attribute__((ext_vector_type(8))) short;
using floatx4 = __attribute__((ext_vector_type(4))) float;

__device__ inline u16 f2bf(float f) {
  union { float f; unsigned u; } v; v.f = f;
  unsigned u = v.u;
  return (u16)((u + 0x7fffu + ((u >> 16) & 1u)) >> 16);  // RNE
}
__device__ inline float bf2f(u16 h) {
  union { unsigned u; float f; } v; v.u = ((unsigned)h) << 16; return v.f;
}

__device__ inline float fsigmoid(float s) { return 1.f / (1.f + __expf(-s)); }
__device__ inline float ftanh(float a) {
  a = fminf(fmaxf(a, -15.f), 15.f);
  float e = __expf(2.f * a);
  return (e - 1.f) / (e + 1.f);
}

// ---------------- fused init: states + cnt zero ----------------
__global__ void k_init_all(u16* __restrict__ ip_state, u16* __restrict__ conn_state,
                           const float* __restrict__ feat, int* __restrict__ cnt) {
  int i = blockIdx.x * blockDim.x + threadIdx.x;
  const int nip = N_IP * D;
  const int nstate = (N_IP + N_CONN) * D;
  if (i < nip) {
    ip_state[i] = 0x3F80;  // bf16(1.0)
  } else if (i < nstate) {
    int j = i - nip;
    int r = j >> 7, c = j & 127;
    conn_state[j] = (c < NF) ? f2bf(feat[r * NF + c]) : (u16)0;
  }
  if (i < N_CONN + N_IP) cnt[i] = 0;
}

// ---------------- fused weight prep (all matrices, bf16 [col][k]) ----------------
__global__ void k_prep_all(
    const float* __restrict__ gik, const float* __restrict__ gir,
    const float* __restrict__ gck, const float* __restrict__ gcr,
    const float* __restrict__ Wm1, const float* __restrict__ Wm2,
    const float* __restrict__ Wr1, const float* __restrict__ Wr2,
    u16* __restrict__ gikb, u16* __restrict__ girb,
    u16* __restrict__ gckb, u16* __restrict__ gcrb,
    u16* __restrict__ wm1b, u16* __restrict__ wm2b,
    u16* __restrict__ wm1t, u16* __restrict__ wm2t,
    u16* __restrict__ wr1b, u16* __restrict__ wr2b) {
  int i = blockIdx.x * blockDim.x + threadIdx.x;
  if (i < 196608) {  // 4 GRU mats (128x384 -> [col][k] 384x128)
    int m = i / 49152, r = i % 49152;
    const float* W = (m == 0) ? gik : (m == 1) ? gir : (m == 2) ? gck : gcr;
    u16* Wb = (m == 0) ? gikb : (m == 1) ? girb : (m == 2) ? gckb : gcrb;
    int col = r >> 7, k = r & 127;
    Wb[r] = f2bf(W[k * 384 + col]);
  } else if (i < 278528) {  // 5 x 128x128 blocks
    int j = i - 196608;
    int m = j / 16384, r = j % 16384;
    const float* W; u16* Wb; int k0;
    if (m == 0) { W = Wm1; Wb = wm1b; k0 = 128; }
    else if (m == 1) { W = Wm2; Wb = wm2b; k0 = 128; }
    else if (m == 2) { W = Wm1; Wb = wm1t; k0 = 0; }
    else if (m == 3) { W = Wm2; Wb = wm2t; k0 = 0; }
    else { W = Wr1; Wb = wr1b; k0 = 0; }
    int col = r >> 7, k = r & 127;
    Wb[r] = f2bf(W[(k0 + k) * 128 + col]);
  } else if (i < 286720) {  // Wr2 128x64 -> [col][k] 64x128
    int r = i - 278528;
    int col = r >> 7, k = r & 127;
    wr2b[r] = f2bf(Wr2[k * 64 + col]);
  }
}

__global__ void k_count(const int* __restrict__ d1, const int* __restrict__ d2,
                        int* __restrict__ c1, int* __restrict__ c2) {
  int e = blockIdx.x * blockDim.x + threadIdx.x;
  if (e >= NE) return;
  atomicAdd(&c1[d1[e]], 1);
  atomicAdd(&c2[d2[e]], 1);
}

// ---------------- merged 3-pass exclusive scan (both segment arrays) ----------------
__global__ void k_scan_part2(const int* __restrict__ cnt1, int* __restrict__ bsum1,
                             int n1, int nb1,
                             const int* __restrict__ cnt2, int* __restrict__ bsum2, int n2) {
  const int* cnt; int* bsum; int n, b;
  if ((int)blockIdx.x < nb1) { cnt = cnt1; bsum = bsum1; n = n1; b = blockIdx.x; }
  else { cnt = cnt2; bsum = bsum2; n = n2; b = blockIdx.x - nb1; }
  int t = threadIdx.x;
  int base = b * 1024 + t * 4;
  int s = 0;
#pragma unroll
  for (int i = 0; i < 4; i++) { int j = base + i; if (j < n) s += cnt[j]; }
  for (int d = 32; d > 0; d >>= 1) s += __shfl_xor(s, d, 64);
  __shared__ int wred[4];
  int lane = t & 63, wv = t >> 6;
  if (lane == 0) wred[wv] = s;
  __syncthreads();
  if (t == 0) bsum[b] = wred[0] + wred[1] + wred[2] + wred[3];
}

__device__ inline void scan_mid_body(int* bsum, int m, int t) {
  int v = (t < m) ? bsum[t] : 0;
  int lane = t & 63, wv = t >> 6;
  int x = v;
  for (int d = 1; d < 64; d <<= 1) { int y = __shfl_up(x, d, 64); if (lane >= d) x += y; }
  __shared__ int wsum[4];
  if (lane == 63) wsum[wv] = x;
  __syncthreads();
  int add = 0;
  for (int i = 0; i < wv; i++) add += wsum[i];
  int ex = add + x - v;
  if (t < m) bsum[t] = ex;
  __syncthreads();
}

__global__ void k_scan_mid2(int* __restrict__ bsum1, int m1, int* __restrict__ bsum2, int m2) {
  int t = threadIdx.x;
  scan_mid_body(bsum1, m1, t);
  scan_mid_body(bsum2, m2, t);
}

// pass 3: write off AND cur
__global__ void k_scan_final2(const int* __restrict__ cnt1, const int* __restrict__ bsum1,
                              int* __restrict__ off1, int* __restrict__ cur1, int n1, int nb1,
                              const int* __restrict__ cnt2, const int* __restrict__ bsum2,
                              int* __restrict__ off2, int* __restrict__ cur2, int n2) {
  const int* cnt; const int* bsum; int* off; int* cur; int n, b;
  if ((int)blockIdx.x < nb1) {
    cnt = cnt1; bsum = bsum1; off = off1; cur = cur1; n = n1; b = blockIdx.x;
  } else {
    cnt = cnt2; bsum = bsum2; off = off2; cur = cur2; n = n2; b = blockIdx.x - nb1;
  }
  int t = threadIdx.x;
  int base = b * 1024 + t * 4;
  int vals[4]; int s = 0;
#pragma unroll
  for (int i = 0; i < 4; i++) {
    int j = base + i;
    vals[i] = (j < n) ? cnt[j] : 0;
    s += vals[i];
  }
  int lane = t & 63, wv = t >> 6;
  int x = s;
  for (int d = 1; d < 64; d <<= 1) { int y = __shfl_up(x, d, 64); if (lane >= d) x += y; }
  __shared__ int wsum[4];
  if (lane == 63) wsum[wv] = x;
  __syncthreads();
  int add = 0;
  for (int i = 0; i < wv; i++) add += wsum[i];
  int run = add + x - s + bsum[b];
#pragma unroll
  for (int i = 0; i < 4; i++) {
    int j = base + i;
    if (j < n) { off[j] = run; cur[j] = run; }
    run += vals[i];
  }
}

__global__ void k_scatter(const int* __restrict__ s1, const int* __restrict__ d1,
                          const int* __restrict__ s2, const int* __restrict__ d2,
                          int* __restrict__ cur1, int* __restrict__ cur2,
                          int* __restrict__ o1, int* __restrict__ o2) {
  int e = blockIdx.x * blockDim.x + threadIdx.x;
  if (e >= NE) return;
  int p1 = atomicAdd(&cur1[d1[e]], 1);
  o1[p1] = s1[e];
  int p2 = atomicAdd(&cur2[d2[e]], 1);
  o2[p2] = s2[e];
}

// ---------------- merged P-GEMM (bf16 in/out): P = S @ Wt^T ----------------
__global__ __launch_bounds__(256) void k_gemmP(
    const u16* __restrict__ S1, const u16* __restrict__ Wt1, u16* __restrict__ P1,
    int M1, int tiles1,
    const u16* __restrict__ S2, const u16* __restrict__ Wt2, u16* __restrict__ P2,
    int M2) {
  __shared__ __align__(16) u16 Wls[128 * 128];  // 32KB; reused as C (64x136)
  const u16* S; const u16* Wt; u16* P; int M, bm;
  if ((int)blockIdx.x < tiles1) { S = S1; Wt = Wt1; P = P1; M = M1; bm = blockIdx.x * 64; }
  else { S = S2; Wt = Wt2; P = P2; M = M2; bm = (blockIdx.x - tiles1) * 64; }
  const int tid = threadIdx.x, wv = tid >> 6, lane = tid & 63;
  const int lrow = lane & 15, quad = lane >> 4;
#pragma unroll
  for (int i = 0; i < 8; i++) {  // stage W swizzled
    int task = i * 256 + tid;
    int col = task >> 4, gr = task & 15;
    uint4 v = *(const uint4*)(Wt + (size_t)col * 128 + gr * 8);
    *(uint4*)(Wls + (size_t)col * 128 + ((gr ^ (col & 15)) * 8)) = v;
  }
  const int arow = bm + wv * 16 + lrow;
  const bool arv = arow < M;
  const bf16x8 zv = {0, 0, 0, 0, 0, 0, 0, 0};
  bf16x8 a[4];
#pragma unroll
  for (int ks = 0; ks < 4; ks++)
    a[ks] = arv ? *(const bf16x8*)(S + (size_t)arow * 128 + quad * 8 + ks * 32) : zv;
  __syncthreads();
  floatx4 acc[8];
#pragma unroll
  for (int ct = 0; ct < 8; ct++) acc[ct] = {0.f, 0.f, 0.f, 0.f};
#pragma unroll
  for (int ks = 0; ks < 4; ks++) {
#pragma unroll
    for (int ct = 0; ct < 8; ct++) {
      int col = ct * 16 + lrow;
      bf16x8 b = *(const bf16x8*)(Wls + (size_t)col * 128 + (((4 * ks + quad) ^ lrow) * 8));
      acc[ct] = __builtin_amdgcn_mfma_f32_16x16x32_bf16(a[ks], b, acc[ct], 0, 0, 0);
    }
  }
  __syncthreads();  // W reads done; reuse as C
  u16* Cls = Wls;   // 64 x 136
#pragma unroll
  for (int ct = 0; ct < 8; ct++) {
    int col = ct * 16 + lrow;
#pragma unroll
    for (int reg = 0; reg < 4; reg++) {
      int lr = wv * 16 + quad * 4 + reg;
      Cls[(size_t)lr * 136 + col] = f2bf(acc[ct][reg]);
    }
  }
  __syncthreads();
#pragma unroll
  for (int i = 0; i < 4; i++) {  // coalesced bf16 write-out
    int task = i * 256 + tid;
    int row = task >> 4, c8 = task & 15;
    int gr2 = bm + row;
    if (gr2 < M)
      *(uint4*)(P + (size_t)gr2 * 128 + c8 * 8) = *(const uint4*)(Cls + (size_t)row * 136 + c8 * 8);
  }
}

// ---------------- fused message+GRU: Q-GEMM + gather-mean + GRU, per 64-node block ----------------
// round-11 structure (best known) + 3 blocks/CU (LDS 49.7KB x3 = 149KB < 160KB;
// VGPR cap ~170 at (256,3), measured use 72 -- no spill) + off/cnt cached in LDS.
__global__ __launch_bounds__(256, 3) void k_msggru(
    u16* __restrict__ st1, const u16* __restrict__ wq1, const float* __restrict__ qb1,
    const u16* __restrict__ P1g, const int* __restrict__ srcs1g,
    const int* __restrict__ off1g, const int* __restrict__ cnt1g,
    const u16* __restrict__ wx1, const u16* __restrict__ wh1, const float* __restrict__ gb1,
    int r1, int tiles1,
    u16* __restrict__ st2, const u16* __restrict__ wq2, const float* __restrict__ qb2,
    const u16* __restrict__ P2g, const int* __restrict__ srcs2g,
    const int* __restrict__ off2g, const int* __restrict__ cnt2g,
    const u16* __restrict__ wx2, const u16* __restrict__ wh2, const float* __restrict__ gb2,
    int r2) {
  __shared__ __align__(16) char smem[49152];
  __shared__ int offLs[64];
  __shared__ int cntLs[64];
  u16* Wq = (u16*)smem;                    // phase A: 128x128 bf16 swizzled (32KB)
  u16* Qb = (u16*)smem;                    // phase B: 64x128 bf16 (16KB)
  u16* Xb = (u16*)(smem + 16384);          // phase B: 64x128 bf16 swizzled (16KB)
  u16* Wg = (u16*)smem;                    // phase C: 6x16x128 bf16 swizzled (24KB)
  u16* Hls = (u16*)(smem + 32768);         // 64x128 bf16 swizzled (16KB), whole kernel
  u16* H; const u16* Wqb; const float* qbias; const u16* P;
  const int* srcs; const int* off; const int* cnt;
  const u16* Wxb; const u16* Whb; const float* gbias; int rows, bm;
  if ((int)blockIdx.x < tiles1) {
    H = st1; Wqb = wq1; qbias = qb1; P = P1g; srcs = srcs1g; off = off1g; cnt = cnt1g;
    Wxb = wx1; Whb = wh1; gbias = gb1; rows = r1; bm = blockIdx.x * 64;
  } else {
    H = st2; Wqb = wq2; qbias = qb2; P = P2g; srcs = srcs2g; off = off2g; cnt = cnt2g;
    Wxb = wx2; Whb = wh2; gbias = gb2; rows = r2; bm = (blockIdx.x - tiles1) * 64;
  }
  const int tid = threadIdx.x, wv = tid >> 6, lane = tid & 63;
  const int lrow = lane & 15, quad = lane >> 4;
  const uint4 z4 = {0, 0, 0, 0};
  // --- phase A: stage Wq (swizzled) + H (swizzled) + off/cnt ---
#pragma unroll
  for (int i = 0; i < 8; i++) {
    int task = i * 256 + tid;
    int col = task >> 4, gr = task & 15;
    uint4 v = *(const uint4*)(Wqb + (size_t)col * 128 + gr * 8);
    *(uint4*)(Wq + (size_t)col * 128 + ((gr ^ (col & 15)) * 8)) = v;
  }
#pragma unroll
  for (int i = 0; i < 4; i++) {
    int task = i * 256 + tid;
    int row = task >> 4, g = task & 15;
    int grow = bm + row;
    uint4 v = (grow < rows) ? *(const uint4*)(H + (size_t)grow * 128 + g * 8) : z4;
    *(uint4*)(Hls + (size_t)row * 128 + ((g ^ (row & 15)) * 8)) = v;
  }
  if (tid < 64) {
    int node = bm + tid;
    offLs[tid] = (node < rows) ? off[node] : 0;
    cntLs[tid] = (node < rows) ? cnt[node] : 0;
  }
  __syncthreads();
  // state A-frags (serve Q-GEMM and GRU h-GEMM)
  bf16x8 ah[4];
#pragma unroll
  for (int ks = 0; ks < 4; ks++)
    ah[ks] = *(const bf16x8*)(Hls + (size_t)(wv * 16 + lrow) * 128 + (((ks * 4 + quad) ^ lrow) * 8));
  // --- Q-GEMM: Q = state @ Wq^T ---
  floatx4 acc[8];
#pragma unroll
  for (int ct = 0; ct < 8; ct++) acc[ct] = {0.f, 0.f, 0.f, 0.f};
#pragma unroll
  for (int ks = 0; ks < 4; ks++) {
#pragma unroll
    for (int ct = 0; ct < 8; ct++) {
      int col = ct * 16 + lrow;
      bf16x8 b = *(const bf16x8*)(Wq + (size_t)col * 128 + (((4 * ks + quad) ^ lrow) * 8));
      acc[ct] = __builtin_amdgcn_mfma_f32_16x16x32_bf16(ah[ks], b, acc[ct], 0, 0, 0);
    }
  }
  __syncthreads();  // Wq reads done; region0 becomes Qb/Xb
  // --- write Q (+bias) as bf16, plain [row][col] ---
#pragma unroll
  for (int ct = 0; ct < 8; ct++) {
    int col = ct * 16 + lrow;
    float bv = qbias[col];
#pragma unroll
    for (int reg = 0; reg < 4; reg++) {
      int lr = wv * 16 + quad * 4 + reg;
      Qb[(size_t)lr * 128 + col] = f2bf(acc[ct][reg] + bv);
    }
  }
  __syncthreads();
  // --- gather-mean: X[node] = mean_e relu(P[src_e] + Q[node]) -> Xb (swizzled) ---
#pragma unroll
  for (int it = 0; it < 4; it++) {
    int task = it * 256 + tid;
    int nl = task >> 4, g = task & 15;
    int node = bm + nl;
    if (node >= rows) continue;
    int c8 = g << 3;
    float q[8];
    {
      uint4 qv = *(const uint4*)(Qb + (size_t)nl * 128 + c8);
      unsigned qq[4] = {qv.x, qv.y, qv.z, qv.w};
#pragma unroll
      for (int k = 0; k < 4; k++) {
        q[2 * k] = __uint_as_float(qq[k] << 16);
        q[2 * k + 1] = __uint_as_float(qq[k] & 0xffff0000u);
      }
    }
    float acg[8] = {0.f, 0.f, 0.f, 0.f, 0.f, 0.f, 0.f, 0.f};
    int o = offLs[nl], n = cntLs[nl];
    int i = 0;
    for (; i + 4 <= n; i += 4) {
      int s0 = srcs[o + i], s1 = srcs[o + i + 1], s2 = srcs[o + i + 2], s3 = srcs[o + i + 3];
      uint4 v0 = *(const uint4*)(P + (size_t)s0 * 128 + c8);
      uint4 v1 = *(const uint4*)(P + (size_t)s1 * 128 + c8);
      uint4 v2 = *(const uint4*)(P + (size_t)s2 * 128 + c8);
      uint4 v3 = *(const uint4*)(P + (size_t)s3 * 128 + c8);
      unsigned w[16] = {v0.x, v0.y, v0.z, v0.w, v1.x, v1.y, v1.z, v1.w,
                        v2.x, v2.y, v2.z, v2.w, v3.x, v3.y, v3.z, v3.w};
#pragma unroll
      for (int e = 0; e < 4; e++)
#pragma unroll
        for (int k = 0; k < 4; k++) {
          unsigned ww = w[e * 4 + k];
          float lo = __uint_as_float(ww << 16);
          float hi = __uint_as_float(ww & 0xffff0000u);
          acg[2 * k] += fmaxf(lo + q[2 * k], 0.f);
          acg[2 * k + 1] += fmaxf(hi + q[2 * k + 1], 0.f);
        }
    }
    for (; i < n; i++) {
      int s0 = srcs[o + i];
      uint4 v0 = *(const uint4*)(P + (size_t)s0 * 128 + c8);
      unsigned w[4] = {v0.x, v0.y, v0.z, v0.w};
#pragma unroll
      for (int k = 0; k < 4; k++) {
        unsigned ww = w[k];
        float lo = __uint_as_float(ww << 16);
        float hi = __uint_as_float(ww & 0xffff0000u);
        acg[2 * k] += fmaxf(lo + q[2 * k], 0.f);
        acg[2 * k + 1] += fmaxf(hi + q[2 * k + 1], 0.f);
      }
    }
    float inv = 1.f / fmaxf((float)n, 1.f);
    bf16x8 ov;
#pragma unroll
    for (int k = 0; k < 8; k++) ov[k] = (short)f2bf(acg[k] * inv);
    *(bf16x8*)(Xb + (size_t)nl * 128 + ((g ^ (nl & 15)) * 8)) = ov;
  }
  __syncthreads();
  // --- x A-frags from Xb ---
  bf16x8 ax[4];
#pragma unroll
  for (int ks = 0; ks < 4; ks++)
    ax[ks] = *(const bf16x8*)(Xb + (size_t)(wv * 16 + lrow) * 128 + (((ks * 4 + quad) ^ lrow) * 8));
  const int lr0 = wv * 16 + quad * 4;
  // --- GRU chunk loop (Wg overlays dead Qb/Xb) ---
  for (int ch = 0; ch < 8; ch++) {
    __syncthreads();  // ch=0: ax/Qb reads done; ch>0: prev Wg reads done
#pragma unroll
    for (int p = 0; p < 2; p++) {
      uint4 v[3];
#pragma unroll
      for (int j = 0; j < 3; j++) {
        int task = (p * 3 + j) * 256 + tid;
        int seg = task >> 8, rem = task & 255;
        int col = rem >> 4, gr = rem & 15;
        const u16* gsrc = (seg < 3 ? Wxb : Whb) +
                          (size_t)((seg < 3 ? seg : seg - 3) * 128 + ch * 16 + col) * 128 + gr * 8;
        v[j] = *(const uint4*)gsrc;
      }
#pragma unroll
      for (int j = 0; j < 3; j++) {
        int task = (p * 3 + j) * 256 + tid;
        int seg = task >> 8, rem = task & 255;
        int col = rem >> 4, gr = rem & 15;
        *(uint4*)(Wg + (size_t)(seg * 16 + col) * 128 + ((gr ^ col) * 8)) = v[j];
      }
    }
    __syncthreads();
    floatx4 gacc[3][2];
#pragma unroll
    for (int g = 0; g < 3; g++) {
      gacc[g][0] = {0.f, 0.f, 0.f, 0.f};
      gacc[g][1] = {0.f, 0.f, 0.f, 0.f};
    }
#pragma unroll
    for (int ks = 0; ks < 4; ks++) {
      int posu = ((4 * ks + quad) ^ lrow) * 8;
#pragma unroll
      for (int g = 0; g < 3; g++) {
        bf16x8 bx = *(const bf16x8*)(Wg + (size_t)(g * 16 + lrow) * 128 + posu);
        bf16x8 bh = *(const bf16x8*)(Wg + (size_t)((3 + g) * 16 + lrow) * 128 + posu);
        gacc[g][0] = __builtin_amdgcn_mfma_f32_16x16x32_bf16(ax[ks], bx, gacc[g][0], 0, 0, 0);
        gacc[g][1] = __builtin_amdgcn_mfma_f32_16x16x32_bf16(ah[ks], bh, gacc[g][1], 0, 0, 0);
      }
    }
    int hcol = ch * 16 + lrow;
    float bxz = gbias[hcol];
    float bxr = gbias[128 + hcol];
    float bxh = gbias[256 + hcol];
    float bhz = gbias[384 + hcol];
    float bhr = gbias[384 + 128 + hcol];
    float bhh = gbias[384 + 256 + hcol];
    int ggr = 2 * ch + (lrow >> 3);
    int gel = lrow & 7;
#pragma unroll
    for (int reg = 0; reg < 4; reg++) {
      int lr = lr0 + reg;
      float xz = gacc[0][0][reg] + bxz;
      float xr = gacc[1][0][reg] + bxr;
      float xh = gacc[2][0][reg] + bxh;
      float hz = gacc[0][1][reg] + bhz;
      float hr = gacc[1][1][reg] + bhr;
      float hh = gacc[2][1][reg] + bhh;
      float z = fsigmoid(xz + hz);
      float rr = fsigmoid(xr + hr);
      float hc = ftanh(xh + rr * hh);
      u16* hp = Hls + (size_t)lr * 128 + ((ggr ^ (lr & 15)) * 8) + gel;
      float hold = bf2f(*hp);
      *hp = f2bf(z * hold + (1.f - z) * hc);
    }
  }
  __syncthreads();
  // --- coalesced state write-out ---
#pragma unroll
  for (int i = 0; i < 4; i++) {
    int task = i * 256 + tid;
    int row = task >> 4, g = task & 15;
    int grow = bm + row;
    if (grow < rows)
      *(uint4*)(H + (size_t)grow * 128 + g * 8) =
          *(const uint4*)(Hls + (size_t)row * 128 + ((g ^ (row & 15)) * 8));
  }
}

// ---------------- fully fused readout: 2 GEMMs + logits + softmax ----------------
__global__ __launch_bounds__(256) void k_readout2(
    const u16* __restrict__ S, const u16* __restrict__ W1b, const float* __restrict__ b1,
    const u16* __restrict__ W2b, const float* __restrict__ b2,
    const float* __restrict__ W3, const float* __restrict__ b3,
    float* __restrict__ out, int M) {
  __shared__ __align__(16) char smem[64 * 132 * 4];  // 33792 B
  u16* Wls = (u16*)smem;
  u16* H1ls = (u16*)smem;
  u16* W2ls = (u16*)(smem + 17408);
  u16* H2ls = (u16*)smem;
  float* W3ls = (float*)(smem + 9216);
  float* b3ls = (float*)(smem + 9216 + 3840);
  const int tid = threadIdx.x, wv = tid >> 6, lane = tid & 63;
  const int lrow = lane & 15, quad = lane >> 4;
  const int bm = blockIdx.x * 64;
#pragma unroll
  for (int i = 0; i < 8; i++) {
    int task = i * 256 + tid;
    int col = task >> 4, gr = task & 15;
    uint4 v = *(const uint4*)(W1b + (size_t)col * 128 + gr * 8);
    *(uint4*)(Wls + (size_t)col * 128 + ((gr ^ (col & 15)) * 8)) = v;
  }
  const int arow = bm + wv * 16 + lrow;
  const bool arv = arow < M;
  const bf16x8 zv = {0, 0, 0, 0, 0, 0, 0, 0};
  bf16x8 a[4];
#pragma unroll
  for (int ks = 0; ks < 4; ks++)
    a[ks] = arv ? *(const bf16x8*)(S + (size_t)arow * 128 + quad * 8 + ks * 32) : zv;
  __syncthreads();
  floatx4 acc1[8];
#pragma unroll
  for (int ct = 0; ct < 8; ct++) acc1[ct] = {0.f, 0.f, 0.f, 0.f};
#pragma unroll
  for (int ks = 0; ks < 4; ks++) {
#pragma unroll
    for (int ct = 0; ct < 8; ct++) {
      int col = ct * 16 + lrow;
      bf16x8 b = *(const bf16x8*)(Wls + (size_t)col * 128 + (((4 * ks + quad) ^ lrow) * 8));
      acc1[ct] = __builtin_amdgcn_mfma_f32_16x16x32_bf16(a[ks], b, acc1[ct], 0, 0, 0);
    }
  }
  __syncthreads();
#pragma unroll
  for (int ct = 0; ct < 8; ct++) {
    int col = ct * 16 + lrow;
    float bv = b1[col];
#pragma unroll
    for (int reg = 0; reg < 4; reg++) {
      int lr = wv * 16 + quad * 4 + reg;
      H1ls[(size_t)lr * 136 + col] = f2bf(fmaxf(acc1[ct][reg] + bv, 0.f));
    }
  }
#pragma unroll
  for (int i = 0; i < 4; i++) {
    int task = i * 256 + tid;
    int col = task >> 4, gr = task & 15;
    uint4 v = *(const uint4*)(W2b + (size_t)col * 128 + gr * 8);
    *(uint4*)(W2ls + (size_t)col * 128 + ((gr ^ (col & 15)) * 8)) = v;
  }
  __syncthreads();
  bf16x8 a2[4];
#pragma unroll
  for (int ks = 0; ks < 4; ks++)
    a2[ks] = *(const bf16x8*)(H1ls + (size_t)(wv * 16 + lrow) * 136 + quad * 8 + ks * 32);
  floatx4 acc2[4];
#pragma unroll
  for (int ct = 0; ct < 4; ct++) acc2[ct] = {0.f, 0.f, 0.f, 0.f};
#pragma unroll
  for (int ks = 0; ks < 4; ks++) {
#pragma unroll
    for (int ct = 0; ct < 4; ct++) {
      int col = ct * 16 + lrow;
      bf16x8 b = *(const bf16x8*)(W2ls + (size_t)col * 128 + (((4 * ks + quad) ^ lrow) * 8));
      acc2[ct] = __builtin_amdgcn_mfma_f32_16x16x32_bf16(a2[ks], b, acc2[ct], 0, 0, 0);
    }
  }
  __syncthreads();
#pragma unroll
  for (int ct = 0; ct < 4; ct++) {
    int col = ct * 16 + lrow;
    float bv = b2[col];
#pragma unroll
    for (int reg = 0; reg < 4; reg++) {
      int lr = wv * 16 + quad * 4 + reg;
      H2ls[(size_t)lr * 72 + col] = f2bf(fmaxf(acc2[ct][reg] + bv, 0.f));
    }
  }
  for (int l = tid; l < 960; l += 256) W3ls[l] = W3[l];
  if (tid < 15) b3ls[tid] = b3[tid];
  __syncthreads();
  if (tid < 64) {
    int row = tid, gr2 = bm + row;
    if (gr2 < M) {
      float lg[15];
#pragma unroll
      for (int c = 0; c < 15; c++) lg[c] = b3ls[c];
      for (int k = 0; k < 64; k++) {
        float hk = bf2f(H2ls[(size_t)row * 72 + k]);
#pragma unroll
        for (int c = 0; c < 15; c++) lg[c] += hk * W3ls[k * 15 + c];
      }
      float m = lg[0];
#pragma unroll
      for (int c = 1; c < 15; c++) m = fmaxf(m, lg[c]);
      float ssum = 0.f;
#pragma unroll
      for (int c = 0; c < 15; c++) { lg[c] = __expf(lg[c] - m); ssum += lg[c]; }
      float inv = 1.f / ssum;
#pragma unroll
      for (int c = 0; c < 15; c++) out[(size_t)gr2 * 15 + c] = lg[c] * inv;
    }
  }
}

// ---------------- launch ----------------
extern "C" void kernel_launch(void* const* d_in, const int* in_sizes, int n_in,
                              void* d_out, int out_size, void* d_ws, size_t ws_size,
                              hipStream_t stream) {
  const float* feat = (const float*)d_in[0];
  const int* src1 = (const int*)d_in[1];
  const int* dst1 = (const int*)d_in[2];
  const int* src2 = (const int*)d_in[3];
  const int* dst2 = (const int*)d_in[4];
  const float* Wm1 = (const float*)d_in[5];
  const float* bm1 = (const float*)d_in[6];
  const float* Wm2 = (const float*)d_in[7];
  const float* bm2 = (const float*)d_in[8];
  const float* gik = (const float*)d_in[9];
  const float* gir = (const float*)d_in[10];
  const float* gib = (const float*)d_in[11];
  const float* gck = (const float*)d_in[12];
  const float* gcr = (const float*)d_in[13];
  const float* gcb = (const float*)d_in[14];
  const float* Wr1 = (const float*)d_in[15];
  const float* br1 = (const float*)d_in[16];
  const float* Wr2 = (const float*)d_in[17];
  const float* br2 = (const float*)d_in[18];
  const float* Wr3 = (const float*)d_in[19];
  const float* br3 = (const float*)d_in[20];
  float* out = (float*)d_out;

  // ---- workspace layout (u16 units) ----
  u16* w16 = (u16*)d_ws;
  size_t o = 0;
  u16* ip_state = w16 + o;   o += (size_t)N_IP * D;
  u16* conn_state = w16 + o; o += (size_t)N_CONN * D;
  u16* P1 = w16 + o;         o += (size_t)N_IP * D;
  u16* P2 = w16 + o;         o += (size_t)N_CONN * D;
  u16* gikb = w16 + o;       o += 49152;
  u16* girb = w16 + o;       o += 49152;
  u16* gckb = w16 + o;       o += 49152;
  u16* gcrb = w16 + o;       o += 49152;
  u16* wm1b = w16 + o;       o += 16384;
  u16* wm2b = w16 + o;       o += 16384;
  u16* wm1t = w16 + o;       o += 16384;
  u16* wm2t = w16 + o;       o += 16384;
  u16* wr1b = w16 + o;       o += 16384;
  u16* wr2b = w16 + o;       o += 8192;
  int* ip = (int*)(w16 + o);
  int* cnt1 = ip;  ip += N_CONN;
  int* cnt2 = ip;  ip += N_IP;
  int* off1 = ip;  ip += N_CONN;
  int* off2 = ip;  ip += N_IP;
  int* cur1 = ip;  ip += N_CONN;
  int* cur2 = ip;  ip += N_IP;
  int* srcs1 = ip; ip += NE;
  int* srcs2 = ip; ip += NE;
  int* bsum1 = ip; ip += 256;
  int* bsum2 = ip; ip += 256;

  const int BT = 256;

  // ---- fused init + weight prep ----
  const int nstate = (N_IP + N_CONN) * D;
  k_init_all<<<(nstate + BT - 1) / BT, BT, 0, stream>>>(ip_state, conn_state, feat, cnt1);
  k_prep_all<<<(286720 + BT - 1) / BT, BT, 0, stream>>>(
      gik, gir, gck, gcr, Wm1, Wm2, Wr1, Wr2,
      gikb, girb, gckb, gcrb, wm1b, wm2b, wm1t, wm2t, wr1b, wr2b);

  // ---- build CSR ----
  k_count<<<(NE + BT - 1) / BT, BT, 0, stream>>>(dst1, dst2, cnt1, cnt2);
  const int nb1 = (N_CONN + 1023) / 1024, nb2 = (N_IP + 1023) / 1024;
  k_scan_part2<<<nb1 + nb2, 256, 0, stream>>>(cnt1, bsum1, N_CONN, nb1, cnt2, bsum2, N_IP);
  k_scan_mid2<<<1, 256, 0, stream>>>(bsum1, nb1, bsum2, nb2);
  k_scan_final2<<<nb1 + nb2, 256, 0, stream>>>(cnt1, bsum1, off1, cur1, N_CONN, nb1,
                                               cnt2, bsum2, off2, cur2, N_IP);
  k_scatter<<<(NE + BT - 1) / BT, BT, 0, stream>>>(src1, dst1, src2, dst2,
                                                   cur1, cur2, srcs1, srcs2);

  const int t64ip = (N_IP + 63) / 64;       // 313
  const int t64cn = (N_CONN + 63) / 64;     // 1563

  for (int t = 0; t < T_ROUNDS; t++) {
    // P1 = old ip_state @ Wm1_top; P2 = old conn_state @ Wm2_top
    k_gemmP<<<t64ip + t64cn, 256, 0, stream>>>(ip_state, wm1t, P1, N_IP, t64ip,
                                               conn_state, wm2t, P2, N_CONN);
    // fused Q-GEMM + gather-mean + GRU for both node types
    k_msggru<<<t64cn + t64ip, 256, 0, stream>>>(
        conn_state, wm1b, bm1, P1, srcs1, off1, cnt1, gckb, gcrb, gcb, N_CONN, t64cn,
        ip_state, wm2b, bm2, P2, srcs2, off2, cnt2, gikb, girb, gib, N_IP);
  }

  k_readout2<<<t64cn, 256, 0, stream>>>(conn_state, wr1b, br1, wr2b, br2,
                                        Wr3, br3, out, N_CONN);
}

// Round 14
// 514.448 us; speedup vs baseline: 1.1266x; 1.0030x over previous
//
#include <hip/hip_runtime.h>
#include <math.h>

#define D 128
#define NF 10
#define N_IP 20000
#define N_CONN 100000
#define NE 200000
#define T_ROUNDS 3

typedef unsigned short u16;
using bf16x8 = __attribute__((ext_vector_type(8))) short;
using floatx4 = __attribute__((ext_vector_type(4))) float;

__device__ inline u16 f2bf(float f) {
  union { float f; unsigned u; } v; v.f = f;
  unsigned u = v.u;
  return (u16)((u + 0x7fffu + ((u >> 16) & 1u)) >> 16);  // RNE
}
__device__ inline float bf2f(u16 h) {
  union { unsigned u; float f; } v; v.u = ((unsigned)h) << 16; return v.f;
}

__device__ inline float fsigmoid(float s) { return 1.f / (1.f + __expf(-s)); }
__device__ inline float ftanh(float a) {
  a = fminf(fmaxf(a, -15.f), 15.f);
  float e = __expf(2.f * a);
  return (e - 1.f) / (e + 1.f);
}

// ---------------- fused init: states + cnt zero ----------------
__global__ void k_init_all(u16* __restrict__ ip_state, u16* __restrict__ conn_state,
                           const float* __restrict__ feat, int* __restrict__ cnt) {
  int i = blockIdx.x * blockDim.x + threadIdx.x;
  const int nip = N_IP * D;
  const int nstate = (N_IP + N_CONN) * D;
  if (i < nip) {
    ip_state[i] = 0x3F80;  // bf16(1.0)
  } else if (i < nstate) {
    int j = i - nip;
    int r = j >> 7, c = j & 127;
    conn_state[j] = (c < NF) ? f2bf(feat[r * NF + c]) : (u16)0;
  }
  if (i < N_CONN + N_IP) cnt[i] = 0;
}

// ---------------- fused weight prep (all matrices, bf16 [col][k]) ----------------
__global__ void k_prep_all(
    const float* __restrict__ gik, const float* __restrict__ gir,
    const float* __restrict__ gck, const float* __restrict__ gcr,
    const float* __restrict__ Wm1, const float* __restrict__ Wm2,
    const float* __restrict__ Wr1, const float* __restrict__ Wr2,
    u16* __restrict__ gikb, u16* __restrict__ girb,
    u16* __restrict__ gckb, u16* __restrict__ gcrb,
    u16* __restrict__ wm1b, u16* __restrict__ wm2b,
    u16* __restrict__ wm1t, u16* __restrict__ wm2t,
    u16* __restrict__ wr1b, u16* __restrict__ wr2b) {
  int i = blockIdx.x * blockDim.x + threadIdx.x;
  if (i < 196608) {  // 4 GRU mats (128x384 -> [col][k] 384x128)
    int m = i / 49152, r = i % 49152;
    const float* W = (m == 0) ? gik : (m == 1) ? gir : (m == 2) ? gck : gcr;
    u16* Wb = (m == 0) ? gikb : (m == 1) ? girb : (m == 2) ? gckb : gcrb;
    int col = r >> 7, k = r & 127;
    Wb[r] = f2bf(W[k * 384 + col]);
  } else if (i < 278528) {  // 5 x 128x128 blocks
    int j = i - 196608;
    int m = j / 16384, r = j % 16384;
    const float* W; u16* Wb; int k0;
    if (m == 0) { W = Wm1; Wb = wm1b; k0 = 128; }
    else if (m == 1) { W = Wm2; Wb = wm2b; k0 = 128; }
    else if (m == 2) { W = Wm1; Wb = wm1t; k0 = 0; }
    else if (m == 3) { W = Wm2; Wb = wm2t; k0 = 0; }
    else { W = Wr1; Wb = wr1b; k0 = 0; }
    int col = r >> 7, k = r & 127;
    Wb[r] = f2bf(W[(k0 + k) * 128 + col]);
  } else if (i < 286720) {  // Wr2 128x64 -> [col][k] 64x128
    int r = i - 278528;
    int col = r >> 7, k = r & 127;
    wr2b[r] = f2bf(Wr2[k * 64 + col]);
  }
}

__global__ void k_count(const int* __restrict__ d1, const int* __restrict__ d2,
                        int* __restrict__ c1, int* __restrict__ c2) {
  int e = blockIdx.x * blockDim.x + threadIdx.x;
  if (e >= NE) return;
  atomicAdd(&c1[d1[e]], 1);
  atomicAdd(&c2[d2[e]], 1);
}

// ---------------- merged 3-pass exclusive scan (both segment arrays) ----------------
__global__ void k_scan_part2(const int* __restrict__ cnt1, int* __restrict__ bsum1,
                             int n1, int nb1,
                             const int* __restrict__ cnt2, int* __restrict__ bsum2, int n2) {
  const int* cnt; int* bsum; int n, b;
  if ((int)blockIdx.x < nb1) { cnt = cnt1; bsum = bsum1; n = n1; b = blockIdx.x; }
  else { cnt = cnt2; bsum = bsum2; n = n2; b = blockIdx.x - nb1; }
  int t = threadIdx.x;
  int base = b * 1024 + t * 4;
  int s = 0;
#pragma unroll
  for (int i = 0; i < 4; i++) { int j = base + i; if (j < n) s += cnt[j]; }
  for (int d = 32; d > 0; d >>= 1) s += __shfl_xor(s, d, 64);
  __shared__ int wred[4];
  int lane = t & 63, wv = t >> 6;
  if (lane == 0) wred[wv] = s;
  __syncthreads();
  if (t == 0) bsum[b] = wred[0] + wred[1] + wred[2] + wred[3];
}

__device__ inline void scan_mid_body(int* bsum, int m, int t) {
  int v = (t < m) ? bsum[t] : 0;
  int lane = t & 63, wv = t >> 6;
  int x = v;
  for (int d = 1; d < 64; d <<= 1) { int y = __shfl_up(x, d, 64); if (lane >= d) x += y; }
  __shared__ int wsum[4];
  if (lane == 63) wsum[wv] = x;
  __syncthreads();
  int add = 0;
  for (int i = 0; i < wv; i++) add += wsum[i];
  int ex = add + x - v;
  if (t < m) bsum[t] = ex;
  __syncthreads();
}

__global__ void k_scan_mid2(int* __restrict__ bsum1, int m1, int* __restrict__ bsum2, int m2) {
  int t = threadIdx.x;
  scan_mid_body(bsum1, m1, t);
  scan_mid_body(bsum2, m2, t);
}

// pass 3: write off AND cur
__global__ void k_scan_final2(const int* __restrict__ cnt1, const int* __restrict__ bsum1,
                              int* __restrict__ off1, int* __restrict__ cur1, int n1, int nb1,
                              const int* __restrict__ cnt2, const int* __restrict__ bsum2,
                              int* __restrict__ off2, int* __restrict__ cur2, int n2) {
  const int* cnt; const int* bsum; int* off; int* cur; int n, b;
  if ((int)blockIdx.x < nb1) {
    cnt = cnt1; bsum = bsum1; off = off1; cur = cur1; n = n1; b = blockIdx.x;
  } else {
    cnt = cnt2; bsum = bsum2; off = off2; cur = cur2; n = n2; b = blockIdx.x - nb1;
  }
  int t = threadIdx.x;
  int base = b * 1024 + t * 4;
  int vals[4]; int s = 0;
#pragma unroll
  for (int i = 0; i < 4; i++) {
    int j = base + i;
    vals[i] = (j < n) ? cnt[j] : 0;
    s += vals[i];
  }
  int lane = t & 63, wv = t >> 6;
  int x = s;
  for (int d = 1; d < 64; d <<= 1) { int y = __shfl_up(x, d, 64); if (lane >= d) x += y; }
  __shared__ int wsum[4];
  if (lane == 63) wsum[wv] = x;
  __syncthreads();
  int add = 0;
  for (int i = 0; i < wv; i++) add += wsum[i];
  int run = add + x - s + bsum[b];
#pragma unroll
  for (int i = 0; i < 4; i++) {
    int j = base + i;
    if (j < n) { off[j] = run; cur[j] = run; }
    run += vals[i];
  }
}

__global__ void k_scatter(const int* __restrict__ s1, const int* __restrict__ d1,
                          const int* __restrict__ s2, const int* __restrict__ d2,
                          int* __restrict__ cur1, int* __restrict__ cur2,
                          int* __restrict__ o1, int* __restrict__ o2) {
  int e = blockIdx.x * blockDim.x + threadIdx.x;
  if (e >= NE) return;
  int p1 = atomicAdd(&cur1[d1[e]], 1);
  o1[p1] = s1[e];
  int p2 = atomicAdd(&cur2[d2[e]], 1);
  o2[p2] = s2[e];
}

// ---------------- merged P-GEMM v2 (bf16 in/out): 128 rows/block ----------------
// W staged once per 128 rows; 2 row-tiles/wave; C bounced per-tile through 17.4KB LDS.
__global__ __launch_bounds__(256) void k_gemmP(
    const u16* __restrict__ S1, const u16* __restrict__ Wt1, u16* __restrict__ P1,
    int M1, int tiles1,
    const u16* __restrict__ S2, const u16* __restrict__ Wt2, u16* __restrict__ P2,
    int M2) {
  __shared__ __align__(16) u16 Wls[128 * 128];  // 32KB; Cls overlays first 17.4KB
  const u16* S; const u16* Wt; u16* P; int M, bm;
  if ((int)blockIdx.x < tiles1) { S = S1; Wt = Wt1; P = P1; M = M1; bm = blockIdx.x * 128; }
  else { S = S2; Wt = Wt2; P = P2; M = M2; bm = (blockIdx.x - tiles1) * 128; }
  const int tid = threadIdx.x, wv = tid >> 6, lane = tid & 63;
  const int lrow = lane & 15, quad = lane >> 4;
#pragma unroll
  for (int i = 0; i < 8; i++) {  // stage W swizzled
    int task = i * 256 + tid;
    int col = task >> 4, gr = task & 15;
    uint4 v = *(const uint4*)(Wt + (size_t)col * 128 + gr * 8);
    *(uint4*)(Wls + (size_t)col * 128 + ((gr ^ (col & 15)) * 8)) = v;
  }
  const bf16x8 zv = {0, 0, 0, 0, 0, 0, 0, 0};
  bf16x8 a[2][4];
#pragma unroll
  for (int tile = 0; tile < 2; tile++) {
    int arow = bm + tile * 64 + wv * 16 + lrow;
    bool arv = arow < M;
#pragma unroll
    for (int ks = 0; ks < 4; ks++)
      a[tile][ks] = arv ? *(const bf16x8*)(S + (size_t)arow * 128 + quad * 8 + ks * 32) : zv;
  }
  __syncthreads();
  floatx4 acc[2][8];
#pragma unroll
  for (int tile = 0; tile < 2; tile++)
#pragma unroll
    for (int ct = 0; ct < 8; ct++) acc[tile][ct] = {0.f, 0.f, 0.f, 0.f};
#pragma unroll
  for (int ks = 0; ks < 4; ks++) {
#pragma unroll
    for (int ct = 0; ct < 8; ct++) {
      int col = ct * 16 + lrow;
      bf16x8 b = *(const bf16x8*)(Wls + (size_t)col * 128 + (((4 * ks + quad) ^ lrow) * 8));
      acc[0][ct] = __builtin_amdgcn_mfma_f32_16x16x32_bf16(a[0][ks], b, acc[0][ct], 0, 0, 0);
      acc[1][ct] = __builtin_amdgcn_mfma_f32_16x16x32_bf16(a[1][ks], b, acc[1][ct], 0, 0, 0);
    }
  }
  u16* Cls = Wls;  // 64 x 136 bounce region
#pragma unroll
  for (int tile = 0; tile < 2; tile++) {
    __syncthreads();  // tile0: W reads done; tile1: prev write-out reads done
#pragma unroll
    for (int ct = 0; ct < 8; ct++) {
      int col = ct * 16 + lrow;
#pragma unroll
      for (int reg = 0; reg < 4; reg++) {
        int lr = wv * 16 + quad * 4 + reg;
        Cls[(size_t)lr * 136 + col] = f2bf(acc[tile][ct][reg]);
      }
    }
    __syncthreads();
#pragma unroll
    for (int i = 0; i < 4; i++) {  // coalesced bf16 write-out (64 rows)
      int task = i * 256 + tid;
      int row = task >> 4, c8 = task & 15;
      int gr2 = bm + tile * 64 + row;
      if (gr2 < M)
        *(uint4*)(P + (size_t)gr2 * 128 + c8 * 8) =
            *(const uint4*)(Cls + (size_t)row * 136 + c8 * 8);
    }
  }
}

// ---------------- fused message+GRU: Q-GEMM + gather-mean + GRU, per 64-node block ----------------
// round-13 structure + next-chunk weight prefetch into NAMED registers (no arrays ->
// no scratch; round-5's spill was the dynamically-indexed v[12] array).
__global__ __launch_bounds__(256, 3) void k_msggru(
    u16* __restrict__ st1, const u16* __restrict__ wq1, const float* __restrict__ qb1,
    const u16* __restrict__ P1g, const int* __restrict__ srcs1g,
    const int* __restrict__ off1g, const int* __restrict__ cnt1g,
    const u16* __restrict__ wx1, const u16* __restrict__ wh1, const float* __restrict__ gb1,
    int r1, int tiles1,
    u16* __restrict__ st2, const u16* __restrict__ wq2, const float* __restrict__ qb2,
    const u16* __restrict__ P2g, const int* __restrict__ srcs2g,
    const int* __restrict__ off2g, const int* __restrict__ cnt2g,
    const u16* __restrict__ wx2, const u16* __restrict__ wh2, const float* __restrict__ gb2,
    int r2) {
  __shared__ __align__(16) char smem[49152];
  __shared__ int offLs[64];
  __shared__ int cntLs[64];
  u16* Wq = (u16*)smem;                    // phase A: 128x128 bf16 swizzled (32KB)
  u16* Qb = (u16*)smem;                    // phase B: 64x128 bf16 (16KB)
  u16* Xb = (u16*)(smem + 16384);          // phase B: 64x128 bf16 swizzled (16KB)
  u16* Wg = (u16*)smem;                    // phase C: 6x16x128 bf16 swizzled (24KB)
  u16* Hls = (u16*)(smem + 32768);         // 64x128 bf16 swizzled (16KB), whole kernel
  u16* H; const u16* Wqb; const float* qbias; const u16* P;
  const int* srcs; const int* off; const int* cnt;
  const u16* Wxb; const u16* Whb; const float* gbias; int rows, bm;
  if ((int)blockIdx.x < tiles1) {
    H = st1; Wqb = wq1; qbias = qb1; P = P1g; srcs = srcs1g; off = off1g; cnt = cnt1g;
    Wxb = wx1; Whb = wh1; gbias = gb1; rows = r1; bm = blockIdx.x * 64;
  } else {
    H = st2; Wqb = wq2; qbias = qb2; P = P2g; srcs = srcs2g; off = off2g; cnt = cnt2g;
    Wxb = wx2; Whb = wh2; gbias = gb2; rows = r2; bm = (blockIdx.x - tiles1) * 64;
  }
  const int tid = threadIdx.x, wv = tid >> 6, lane = tid & 63;
  const int lrow = lane & 15, quad = lane >> 4;
  const uint4 z4 = {0, 0, 0, 0};
  // --- phase A: stage Wq (swizzled) + H (swizzled) + off/cnt ---
#pragma unroll
  for (int i = 0; i < 8; i++) {
    int task = i * 256 + tid;
    int col = task >> 4, gr = task & 15;
    uint4 v = *(const uint4*)(Wqb + (size_t)col * 128 + gr * 8);
    *(uint4*)(Wq + (size_t)col * 128 + ((gr ^ (col & 15)) * 8)) = v;
  }
#pragma unroll
  for (int i = 0; i < 4; i++) {
    int task = i * 256 + tid;
    int row = task >> 4, g = task & 15;
    int grow = bm + row;
    uint4 v = (grow < rows) ? *(const uint4*)(H + (size_t)grow * 128 + g * 8) : z4;
    *(uint4*)(Hls + (size_t)row * 128 + ((g ^ (row & 15)) * 8)) = v;
  }
  if (tid < 64) {
    int node = bm + tid;
    offLs[tid] = (node < rows) ? off[node] : 0;
    cntLs[tid] = (node < rows) ? cnt[node] : 0;
  }
  __syncthreads();
  // state A-frags (serve Q-GEMM and GRU h-GEMM)
  bf16x8 ah[4];
#pragma unroll
  for (int ks = 0; ks < 4; ks++)
    ah[ks] = *(const bf16x8*)(Hls + (size_t)(wv * 16 + lrow) * 128 + (((ks * 4 + quad) ^ lrow) * 8));
  // --- Q-GEMM: Q = state @ Wq^T ---
  floatx4 acc[8];
#pragma unroll
  for (int ct = 0; ct < 8; ct++) acc[ct] = {0.f, 0.f, 0.f, 0.f};
#pragma unroll
  for (int ks = 0; ks < 4; ks++) {
#pragma unroll
    for (int ct = 0; ct < 8; ct++) {
      int col = ct * 16 + lrow;
      bf16x8 b = *(const bf16x8*)(Wq + (size_t)col * 128 + (((4 * ks + quad) ^ lrow) * 8));
      acc[ct] = __builtin_amdgcn_mfma_f32_16x16x32_bf16(ah[ks], b, acc[ct], 0, 0, 0);
    }
  }
  __syncthreads();  // Wq reads done; region0 becomes Qb/Xb
  // --- write Q (+bias) as bf16, plain [row][col] ---
#pragma unroll
  for (int ct = 0; ct < 8; ct++) {
    int col = ct * 16 + lrow;
    float bv = qbias[col];
#pragma unroll
    for (int reg = 0; reg < 4; reg++) {
      int lr = wv * 16 + quad * 4 + reg;
      Qb[(size_t)lr * 128 + col] = f2bf(acc[ct][reg] + bv);
    }
  }
  __syncthreads();
  // --- gather-mean: X[node] = mean_e relu(P[src_e] + Q[node]) -> Xb (swizzled) ---
#pragma unroll
  for (int it = 0; it < 4; it++) {
    int task = it * 256 + tid;
    int nl = task >> 4, g = task & 15;
    int node = bm + nl;
    if (node >= rows) continue;
    int c8 = g << 3;
    float q[8];
    {
      uint4 qv = *(const uint4*)(Qb + (size_t)nl * 128 + c8);
      unsigned qq[4] = {qv.x, qv.y, qv.z, qv.w};
#pragma unroll
      for (int k = 0; k < 4; k++) {
        q[2 * k] = __uint_as_float(qq[k] << 16);
        q[2 * k + 1] = __uint_as_float(qq[k] & 0xffff0000u);
      }
    }
    float acg[8] = {0.f, 0.f, 0.f, 0.f, 0.f, 0.f, 0.f, 0.f};
    int o = offLs[nl], n = cntLs[nl];
    int i = 0;
    for (; i + 4 <= n; i += 4) {
      int s0 = srcs[o + i], s1 = srcs[o + i + 1], s2 = srcs[o + i + 2], s3 = srcs[o + i + 3];
      uint4 v0 = *(const uint4*)(P + (size_t)s0 * 128 + c8);
      uint4 v1 = *(const uint4*)(P + (size_t)s1 * 128 + c8);
      uint4 v2 = *(const uint4*)(P + (size_t)s2 * 128 + c8);
      uint4 v3 = *(const uint4*)(P + (size_t)s3 * 128 + c8);
      unsigned w[16] = {v0.x, v0.y, v0.z, v0.w, v1.x, v1.y, v1.z, v1.w,
                        v2.x, v2.y, v2.z, v2.w, v3.x, v3.y, v3.z, v3.w};
#pragma unroll
      for (int e = 0; e < 4; e++)
#pragma unroll
        for (int k = 0; k < 4; k++) {
          unsigned ww = w[e * 4 + k];
          float lo = __uint_as_float(ww << 16);
          float hi = __uint_as_float(ww & 0xffff0000u);
          acg[2 * k] += fmaxf(lo + q[2 * k], 0.f);
          acg[2 * k + 1] += fmaxf(hi + q[2 * k + 1], 0.f);
        }
    }
    for (; i < n; i++) {
      int s0 = srcs[o + i];
      uint4 v0 = *(const uint4*)(P + (size_t)s0 * 128 + c8);
      unsigned w[4] = {v0.x, v0.y, v0.z, v0.w};
#pragma unroll
      for (int k = 0; k < 4; k++) {
        unsigned ww = w[k];
        float lo = __uint_as_float(ww << 16);
        float hi = __uint_as_float(ww & 0xffff0000u);
        acg[2 * k] += fmaxf(lo + q[2 * k], 0.f);
        acg[2 * k + 1] += fmaxf(hi + q[2 * k + 1], 0.f);
      }
    }
    float inv = 1.f / fmaxf((float)n, 1.f);
    bf16x8 ov;
#pragma unroll
    for (int k = 0; k < 8; k++) ov[k] = (short)f2bf(acg[k] * inv);
    *(bf16x8*)(Xb + (size_t)nl * 128 + ((g ^ (nl & 15)) * 8)) = ov;
  }
  __syncthreads();
  // --- x A-frags from Xb ---
  bf16x8 ax[4];
#pragma unroll
  for (int ks = 0; ks < 4; ks++)
    ax[ks] = *(const bf16x8*)(Xb + (size_t)(wv * 16 + lrow) * 128 + (((ks * 4 + quad) ^ lrow) * 8));
  const int lr0 = wv * 16 + quad * 4;
  // --- per-thread staging pointers (6 tasks), then GRU chunk loop with prefetch ---
  const u16* gp0; const u16* gp1; const u16* gp2;
  const u16* gp3; const u16* gp4; const u16* gp5;
  u16* lp0; u16* lp1; u16* lp2; u16* lp3; u16* lp4; u16* lp5;
  {
#define MK_PTRS(J, GP, LP)                                                      \
    {                                                                           \
      int task = (J) * 256 + tid;                                               \
      int seg = task >> 8, rem = task & 255;                                    \
      int col = rem >> 4, gr = rem & 15;                                        \
      GP = (seg < 3 ? Wxb : Whb) +                                              \
           (size_t)((seg < 3 ? seg : seg - 3) * 128 + col) * 128 + gr * 8;      \
      LP = Wg + (size_t)(seg * 16 + col) * 128 + ((gr ^ col) * 8);              \
    }
    MK_PTRS(0, gp0, lp0) MK_PTRS(1, gp1, lp1) MK_PTRS(2, gp2, lp2)
    MK_PTRS(3, gp3, lp3) MK_PTRS(4, gp4, lp4) MK_PTRS(5, gp5, lp5)
#undef MK_PTRS
  }
  // preload chunk 0 (weights stride per chunk = 16 cols * 128 = 2048 u16)
  uint4 v0 = *(const uint4*)(gp0);
  uint4 v1 = *(const uint4*)(gp1);
  uint4 v2 = *(const uint4*)(gp2);
  uint4 v3 = *(const uint4*)(gp3);
  uint4 v4 = *(const uint4*)(gp4);
  uint4 v5 = *(const uint4*)(gp5);
  for (int ch = 0; ch < 8; ch++) {
    __syncthreads();  // ch=0: ax/Qb reads done; ch>0: prev Wg reads done
    *(uint4*)lp0 = v0; *(uint4*)lp1 = v1; *(uint4*)lp2 = v2;
    *(uint4*)lp3 = v3; *(uint4*)lp4 = v4; *(uint4*)lp5 = v5;
    __syncthreads();
    if (ch < 7) {  // prefetch next chunk; loads in flight across MFMA+epilogue
      size_t d = (size_t)(ch + 1) * 2048;
      v0 = *(const uint4*)(gp0 + d);
      v1 = *(const uint4*)(gp1 + d);
      v2 = *(const uint4*)(gp2 + d);
      v3 = *(const uint4*)(gp3 + d);
      v4 = *(const uint4*)(gp4 + d);
      v5 = *(const uint4*)(gp5 + d);
    }
    floatx4 gacc[3][2];
#pragma unroll
    for (int g = 0; g < 3; g++) {
      gacc[g][0] = {0.f, 0.f, 0.f, 0.f};
      gacc[g][1] = {0.f, 0.f, 0.f, 0.f};
    }
#pragma unroll
    for (int ks = 0; ks < 4; ks++) {
      int posu = ((4 * ks + quad) ^ lrow) * 8;
#pragma unroll
      for (int g = 0; g < 3; g++) {
        bf16x8 bx = *(const bf16x8*)(Wg + (size_t)(g * 16 + lrow) * 128 + posu);
        bf16x8 bh = *(const bf16x8*)(Wg + (size_t)((3 + g) * 16 + lrow) * 128 + posu);
        gacc[g][0] = __builtin_amdgcn_mfma_f32_16x16x32_bf16(ax[ks], bx, gacc[g][0], 0, 0, 0);
        gacc[g][1] = __builtin_amdgcn_mfma_f32_16x16x32_bf16(ah[ks], bh, gacc[g][1], 0, 0, 0);
      }
    }
    int hcol = ch * 16 + lrow;
    float bxz = gbias[hcol];
    float bxr = gbias[128 + hcol];
    float bxh = gbias[256 + hcol];
    float bhz = gbias[384 + hcol];
    float bhr = gbias[384 + 128 + hcol];
    float bhh = gbias[384 + 256 + hcol];
    int ggr = 2 * ch + (lrow >> 3);
    int gel = lrow & 7;
#pragma unroll
    for (int reg = 0; reg < 4; reg++) {
      int lr = lr0 + reg;
      float xz = gacc[0][0][reg] + bxz;
      float xr = gacc[1][0][reg] + bxr;
      float xh = gacc[2][0][reg] + bxh;
      float hz = gacc[0][1][reg] + bhz;
      float hr = gacc[1][1][reg] + bhr;
      float hh = gacc[2][1][reg] + bhh;
      float z = fsigmoid(xz + hz);
      float rr = fsigmoid(xr + hr);
      float hc = ftanh(xh + rr * hh);
      u16* hp = Hls + (size_t)lr * 128 + ((ggr ^ (lr & 15)) * 8) + gel;
      float hold = bf2f(*hp);
      *hp = f2bf(z * hold + (1.f - z) * hc);
    }
  }
  __syncthreads();
  // --- coalesced state write-out ---
#pragma unroll
  for (int i = 0; i < 4; i++) {
    int task = i * 256 + tid;
    int row = task >> 4, g = task & 15;
    int grow = bm + row;
    if (grow < rows)
      *(uint4*)(H + (size_t)grow * 128 + g * 8) =
          *(const uint4*)(Hls + (size_t)row * 128 + ((g ^ (row & 15)) * 8));
  }
}

// ---------------- fully fused readout: 2 GEMMs + logits + softmax ----------------
__global__ __launch_bounds__(256) void k_readout2(
    const u16* __restrict__ S, const u16* __restrict__ W1b, const float* __restrict__ b1,
    const u16* __restrict__ W2b, const float* __restrict__ b2,
    const float* __restrict__ W3, const float* __restrict__ b3,
    float* __restrict__ out, int M) {
  __shared__ __align__(16) char smem[64 * 132 * 4];  // 33792 B
  u16* Wls = (u16*)smem;
  u16* H1ls = (u16*)smem;
  u16* W2ls = (u16*)(smem + 17408);
  u16* H2ls = (u16*)smem;
  float* W3ls = (float*)(smem + 9216);
  float* b3ls = (float*)(smem + 9216 + 3840);
  const int tid = threadIdx.x, wv = tid >> 6, lane = tid & 63;
  const int lrow = lane & 15, quad = lane >> 4;
  const int bm = blockIdx.x * 64;
#pragma unroll
  for (int i = 0; i < 8; i++) {
    int task = i * 256 + tid;
    int col = task >> 4, gr = task & 15;
    uint4 v = *(const uint4*)(W1b + (size_t)col * 128 + gr * 8);
    *(uint4*)(Wls + (size_t)col * 128 + ((gr ^ (col & 15)) * 8)) = v;
  }
  const int arow = bm + wv * 16 + lrow;
  const bool arv = arow < M;
  const bf16x8 zv = {0, 0, 0, 0, 0, 0, 0, 0};
  bf16x8 a[4];
#pragma unroll
  for (int ks = 0; ks < 4; ks++)
    a[ks] = arv ? *(const bf16x8*)(S + (size_t)arow * 128 + quad * 8 + ks * 32) : zv;
  __syncthreads();
  floatx4 acc1[8];
#pragma unroll
  for (int ct = 0; ct < 8; ct++) acc1[ct] = {0.f, 0.f, 0.f, 0.f};
#pragma unroll
  for (int ks = 0; ks < 4; ks++) {
#pragma unroll
    for (int ct = 0; ct < 8; ct++) {
      int col = ct * 16 + lrow;
      bf16x8 b = *(const bf16x8*)(Wls + (size_t)col * 128 + (((4 * ks + quad) ^ lrow) * 8));
      acc1[ct] = __builtin_amdgcn_mfma_f32_16x16x32_bf16(a[ks], b, acc1[ct], 0, 0, 0);
    }
  }
  __syncthreads();
#pragma unroll
  for (int ct = 0; ct < 8; ct++) {
    int col = ct * 16 + lrow;
    float bv = b1[col];
#pragma unroll
    for (int reg = 0; reg < 4; reg++) {
      int lr = wv * 16 + quad * 4 + reg;
      H1ls[(size_t)lr * 136 + col] = f2bf(fmaxf(acc1[ct][reg] + bv, 0.f));
    }
  }
#pragma unroll
  for (int i = 0; i < 4; i++) {
    int task = i * 256 + tid;
    int col = task >> 4, gr = task & 15;
    uint4 v = *(const uint4*)(W2b + (size_t)col * 128 + gr * 8);
    *(uint4*)(W2ls + (size_t)col * 128 + ((gr ^ (col & 15)) * 8)) = v;
  }
  __syncthreads();
  bf16x8 a2[4];
#pragma unroll
  for (int ks = 0; ks < 4; ks++)
    a2[ks] = *(const bf16x8*)(H1ls + (size_t)(wv * 16 + lrow) * 136 + quad * 8 + ks * 32);
  floatx4 acc2[4];
#pragma unroll
  for (int ct = 0; ct < 4; ct++) acc2[ct] = {0.f, 0.f, 0.f, 0.f};
#pragma unroll
  for (int ks = 0; ks < 4; ks++) {
#pragma unroll
    for (int ct = 0; ct < 4; ct++) {
      int col = ct * 16 + lrow;
      bf16x8 b = *(const bf16x8*)(W2ls + (size_t)col * 128 + (((4 * ks + quad) ^ lrow) * 8));
      acc2[ct] = __builtin_amdgcn_mfma_f32_16x16x32_bf16(a2[ks], b, acc2[ct], 0, 0, 0);
    }
  }
  __syncthreads();
#pragma unroll
  for (int ct = 0; ct < 4; ct++) {
    int col = ct * 16 + lrow;
    float bv = b2[col];
#pragma unroll
    for (int reg = 0; reg < 4; reg++) {
      int lr = wv * 16 + quad * 4 + reg;
      H2ls[(size_t)lr * 72 + col] = f2bf(fmaxf(acc2[ct][reg] + bv, 0.f));
    }
  }
  for (int l = tid; l < 960; l += 256) W3ls[l] = W3[l];
  if (tid < 15) b3ls[tid] = b3[tid];
  __syncthreads();
  if (tid < 64) {
    int row = tid, gr2 = bm + row;
    if (gr2 < M) {
      float lg[15];
#pragma unroll
      for (int c = 0; c < 15; c++) lg[c] = b3ls[c];
      for (int k = 0; k < 64; k++) {
        float hk = bf2f(H2ls[(size_t)row * 72 + k]);
#pragma unroll
        for (int c = 0; c < 15; c++) lg[c] += hk * W3ls[k * 15 + c];
      }
      float m = lg[0];
#pragma unroll
      for (int c = 1; c < 15; c++) m = fmaxf(m, lg[c]);
      float ssum = 0.f;
#pragma unroll
      for (int c = 0; c < 15; c++) { lg[c] = __expf(lg[c] - m); ssum += lg[c]; }
      float inv = 1.f / ssum;
#pragma unroll
      for (int c = 0; c < 15; c++) out[(size_t)gr2 * 15 + c] = lg[c] * inv;
    }
  }
}

// ---------------- launch ----------------
extern "C" void kernel_launch(void* const* d_in, const int* in_sizes, int n_in,
                              void* d_out, int out_size, void* d_ws, size_t ws_size,
                              hipStream_t stream) {
  const float* feat = (const float*)d_in[0];
  const int* src1 = (const int*)d_in[1];
  const int* dst1 = (const int*)d_in[2];
  const int* src2 = (const int*)d_in[3];
  const int* dst2 = (const int*)d_in[4];
  const float* Wm1 = (const float*)d_in[5];
  const float* bm1 = (const float*)d_in[6];
  const float* Wm2 = (const float*)d_in[7];
  const float* bm2 = (const float*)d_in[8];
  const float* gik = (const float*)d_in[9];
  const float* gir = (const float*)d_in[10];
  const float* gib = (const float*)d_in[11];
  const float* gck = (const float*)d_in[12];
  const float* gcr = (const float*)d_in[13];
  const float* gcb = (const float*)d_in[14];
  const float* Wr1 = (const float*)d_in[15];
  const float* br1 = (const float*)d_in[16];
  const float* Wr2 = (const float*)d_in[17];
  const float* br2 = (const float*)d_in[18];
  const float* Wr3 = (const float*)d_in[19];
  const float* br3 = (const float*)d_in[20];
  float* out = (float*)d_out;

  // ---- workspace layout (u16 units) ----
  u16* w16 = (u16*)d_ws;
  size_t o = 0;
  u16* ip_state = w16 + o;   o += (size_t)N_IP * D;
  u16* conn_state = w16 + o; o += (size_t)N_CONN * D;
  u16* P1 = w16 + o;         o += (size_t)N_IP * D;
  u16* P2 = w16 + o;         o += (size_t)N_CONN * D;
  u16* gikb = w16 + o;       o += 49152;
  u16* girb = w16 + o;       o += 49152;
  u16* gckb = w16 + o;       o += 49152;
  u16* gcrb = w16 + o;       o += 49152;
  u16* wm1b = w16 + o;       o += 16384;
  u16* wm2b = w16 + o;       o += 16384;
  u16* wm1t = w16 + o;       o += 16384;
  u16* wm2t = w16 + o;       o += 16384;
  u16* wr1b = w16 + o;       o += 16384;
  u16* wr2b = w16 + o;       o += 8192;
  int* ip = (int*)(w16 + o);
  int* cnt1 = ip;  ip += N_CONN;
  int* cnt2 = ip;  ip += N_IP;
  int* off1 = ip;  ip += N_CONN;
  int* off2 = ip;  ip += N_IP;
  int* cur1 = ip;  ip += N_CONN;
  int* cur2 = ip;  ip += N_IP;
  int* srcs1 = ip; ip += NE;
  int* srcs2 = ip; ip += NE;
  int* bsum1 = ip; ip += 256;
  int* bsum2 = ip; ip += 256;

  const int BT = 256;

  // ---- fused init + weight prep ----
  const int nstate = (N_IP + N_CONN) * D;
  k_init_all<<<(nstate + BT - 1) / BT, BT, 0, stream>>>(ip_state, conn_state, feat, cnt1);
  k_prep_all<<<(286720 + BT - 1) / BT, BT, 0, stream>>>(
      gik, gir, gck, gcr, Wm1, Wm2, Wr1, Wr2,
      gikb, girb, gckb, gcrb, wm1b, wm2b, wm1t, wm2t, wr1b, wr2b);

  // ---- build CSR ----
  k_count<<<(NE + BT - 1) / BT, BT, 0, stream>>>(dst1, dst2, cnt1, cnt2);
  const int nb1 = (N_CONN + 1023) / 1024, nb2 = (N_IP + 1023) / 1024;
  k_scan_part2<<<nb1 + nb2, 256, 0, stream>>>(cnt1, bsum1, N_CONN, nb1, cnt2, bsum2, N_IP);
  k_scan_mid2<<<1, 256, 0, stream>>>(bsum1, nb1, bsum2, nb2);
  k_scan_final2<<<nb1 + nb2, 256, 0, stream>>>(cnt1, bsum1, off1, cur1, N_CONN, nb1,
                                               cnt2, bsum2, off2, cur2, N_IP);
  k_scatter<<<(NE + BT - 1) / BT, BT, 0, stream>>>(src1, dst1, src2, dst2,
                                                   cur1, cur2, srcs1, srcs2);

  const int t64ip = (N_IP + 63) / 64;       // 313
  const int t64cn = (N_CONN + 63) / 64;     // 1563
  const int t128ip = (N_IP + 127) / 128;    // 157
  const int t128cn = (N_CONN + 127) / 128;  // 782

  for (int t = 0; t < T_ROUNDS; t++) {
    // P1 = old ip_state @ Wm1_top; P2 = old conn_state @ Wm2_top
    k_gemmP<<<t128ip + t128cn, 256, 0, stream>>>(ip_state, wm1t, P1, N_IP, t128ip,
                                                 conn_state, wm2t, P2, N_CONN);
    // fused Q-GEMM + gather-mean + GRU for both node types
    k_msggru<<<t64cn + t64ip, 256, 0, stream>>>(
        conn_state, wm1b, bm1, P1, srcs1, off1, cnt1, gckb, gcrb, gcb, N_CONN, t64cn,
        ip_state, wm2b, bm2, P2, srcs2, off2, cnt2, gikb, girb, gib, N_IP);
  }

  k_readout2<<<t64cn, 256, 0, stream>>>(conn_state, wr1b, br1, wr2b, br2,
                                        Wr3, br3, out, N_CONN);
}

// Round 16
// 514.098 us; speedup vs baseline: 1.1273x; 1.0007x over previous
//
#include <hip/hip_runtime.h>
#include <math.h>

#define D 128
#define NF 10
#define N_IP 20000
#define N_CONN 100000
#define NE 200000
#define T_ROUNDS 3

typedef unsigned short u16;
using bf16x8 = __attribute__((ext_vector_type(8))) short;
using floatx4 = __attribute__((ext_vector_type(4))) float;

__device__ inline u16 f2bf(float f) {
  union { float f; unsigned u; } v; v.f = f;
  unsigned u = v.u;
  return (u16)((u + 0x7fffu + ((u >> 16) & 1u)) >> 16);  // RNE
}
__device__ inline float bf2f(u16 h) {
  union { unsigned u; float f; } v; v.u = ((unsigned)h) << 16; return v.f;
}

__device__ inline float fsigmoid(float s) { return 1.f / (1.f + __expf(-s)); }
__device__ inline float ftanh(float a) {
  a = fminf(fmaxf(a, -15.f), 15.f);
  float e = __expf(2.f * a);
  return (e - 1.f) / (e + 1.f);
}

// ---------------- fused init: states + cnt zero ----------------
__global__ void k_init_all(u16* __restrict__ ip_state, u16* __restrict__ conn_state,
                           const float* __restrict__ feat, int* __restrict__ cnt) {
  int i = blockIdx.x * blockDim.x + threadIdx.x;
  const int nip = N_IP * D;
  const int nstate = (N_IP + N_CONN) * D;
  if (i < nip) {
    ip_state[i] = 0x3F80;  // bf16(1.0)
  } else if (i < nstate) {
    int j = i - nip;
    int r = j >> 7, c = j & 127;
    conn_state[j] = (c < NF) ? f2bf(feat[r * NF + c]) : (u16)0;
  }
  if (i < N_CONN + N_IP) cnt[i] = 0;
}

// ---------------- fused weight prep (all matrices, bf16 [col][k]) ----------------
__global__ void k_prep_all(
    const float* __restrict__ gik, const float* __restrict__ gir,
    const float* __restrict__ gck, const float* __restrict__ gcr,
    const float* __restrict__ Wm1, const float* __restrict__ Wm2,
    const float* __restrict__ Wr1, const float* __restrict__ Wr2,
    u16* __restrict__ gikb, u16* __restrict__ girb,
    u16* __restrict__ gckb, u16* __restrict__ gcrb,
    u16* __restrict__ wm1b, u16* __restrict__ wm2b,
    u16* __restrict__ wm1t, u16* __restrict__ wm2t,
    u16* __restrict__ wr1b, u16* __restrict__ wr2b) {
  int i = blockIdx.x * blockDim.x + threadIdx.x;
  if (i < 196608) {  // 4 GRU mats (128x384 -> [col][k] 384x128)
    int m = i / 49152, r = i % 49152;
    const float* W = (m == 0) ? gik : (m == 1) ? gir : (m == 2) ? gck : gcr;
    u16* Wb = (m == 0) ? gikb : (m == 1) ? girb : (m == 2) ? gckb : gcrb;
    int col = r >> 7, k = r & 127;
    Wb[r] = f2bf(W[k * 384 + col]);
  } else if (i < 278528) {  // 5 x 128x128 blocks
    int j = i - 196608;
    int m = j / 16384, r = j % 16384;
    const float* W; u16* Wb; int k0;
    if (m == 0) { W = Wm1; Wb = wm1b; k0 = 128; }
    else if (m == 1) { W = Wm2; Wb = wm2b; k0 = 128; }
    else if (m == 2) { W = Wm1; Wb = wm1t; k0 = 0; }
    else if (m == 3) { W = Wm2; Wb = wm2t; k0 = 0; }
    else { W = Wr1; Wb = wr1b; k0 = 0; }
    int col = r >> 7, k = r & 127;
    Wb[r] = f2bf(W[(k0 + k) * 128 + col]);
  } else if (i < 286720) {  // Wr2 128x64 -> [col][k] 64x128
    int r = i - 278528;
    int col = r >> 7, k = r & 127;
    wr2b[r] = f2bf(Wr2[k * 64 + col]);
  }
}

__global__ void k_count(const int* __restrict__ d1, const int* __restrict__ d2,
                        int* __restrict__ c1, int* __restrict__ c2) {
  int e = blockIdx.x * blockDim.x + threadIdx.x;
  if (e >= NE) return;
  atomicAdd(&c1[d1[e]], 1);
  atomicAdd(&c2[d2[e]], 1);
}

// ---------------- merged 3-pass exclusive scan (both segment arrays) ----------------
__global__ void k_scan_part2(const int* __restrict__ cnt1, int* __restrict__ bsum1,
                             int n1, int nb1,
                             const int* __restrict__ cnt2, int* __restrict__ bsum2, int n2) {
  const int* cnt; int* bsum; int n, b;
  if ((int)blockIdx.x < nb1) { cnt = cnt1; bsum = bsum1; n = n1; b = blockIdx.x; }
  else { cnt = cnt2; bsum = bsum2; n = n2; b = blockIdx.x - nb1; }
  int t = threadIdx.x;
  int base = b * 1024 + t * 4;
  int s = 0;
#pragma unroll
  for (int i = 0; i < 4; i++) { int j = base + i; if (j < n) s += cnt[j]; }
  for (int d = 32; d > 0; d >>= 1) s += __shfl_xor(s, d, 64);
  __shared__ int wred[4];
  int lane = t & 63, wv = t >> 6;
  if (lane == 0) wred[wv] = s;
  __syncthreads();
  if (t == 0) bsum[b] = wred[0] + wred[1] + wred[2] + wred[3];
}

__device__ inline void scan_mid_body(int* bsum, int m, int t) {
  int v = (t < m) ? bsum[t] : 0;
  int lane = t & 63, wv = t >> 6;
  int x = v;
  for (int d = 1; d < 64; d <<= 1) { int y = __shfl_up(x, d, 64); if (lane >= d) x += y; }
  __shared__ int wsum[4];
  if (lane == 63) wsum[wv] = x;
  __syncthreads();
  int add = 0;
  for (int i = 0; i < wv; i++) add += wsum[i];
  int ex = add + x - v;
  if (t < m) bsum[t] = ex;
  __syncthreads();
}

__global__ void k_scan_mid2(int* __restrict__ bsum1, int m1, int* __restrict__ bsum2, int m2) {
  int t = threadIdx.x;
  scan_mid_body(bsum1, m1, t);
  scan_mid_body(bsum2, m2, t);
}

// pass 3: write off AND cur
__global__ void k_scan_final2(const int* __restrict__ cnt1, const int* __restrict__ bsum1,
                              int* __restrict__ off1, int* __restrict__ cur1, int n1, int nb1,
                              const int* __restrict__ cnt2, const int* __restrict__ bsum2,
                              int* __restrict__ off2, int* __restrict__ cur2, int n2) {
  const int* cnt; const int* bsum; int* off; int* cur; int n, b;
  if ((int)blockIdx.x < nb1) {
    cnt = cnt1; bsum = bsum1; off = off1; cur = cur1; n = n1; b = blockIdx.x;
  } else {
    cnt = cnt2; bsum = bsum2; off = off2; cur = cur2; n = n2; b = blockIdx.x - nb1;
  }
  int t = threadIdx.x;
  int base = b * 1024 + t * 4;
  int vals[4]; int s = 0;
#pragma unroll
  for (int i = 0; i < 4; i++) {
    int j = base + i;
    vals[i] = (j < n) ? cnt[j] : 0;
    s += vals[i];
  }
  int lane = t & 63, wv = t >> 6;
  int x = s;
  for (int d = 1; d < 64; d <<= 1) { int y = __shfl_up(x, d, 64); if (lane >= d) x += y; }
  __shared__ int wsum[4];
  if (lane == 63) wsum[wv] = x;
  __syncthreads();
  int add = 0;
  for (int i = 0; i < wv; i++) add += wsum[i];
  int run = add + x - s + bsum[b];
#pragma unroll
  for (int i = 0; i < 4; i++) {
    int j = base + i;
    if (j < n) { off[j] = run; cur[j] = run; }
    run += vals[i];
  }
}

__global__ void k_scatter(const int* __restrict__ s1, const int* __restrict__ d1,
                          const int* __restrict__ s2, const int* __restrict__ d2,
                          int* __restrict__ cur1, int* __restrict__ cur2,
                          int* __restrict__ o1, int* __restrict__ o2) {
  int e = blockIdx.x * blockDim.x + threadIdx.x;
  if (e >= NE) return;
  int p1 = atomicAdd(&cur1[d1[e]], 1);
  o1[p1] = s1[e];
  int p2 = atomicAdd(&cur2[d2[e]], 1);
  o2[p2] = s2[e];
}

// ---------------- merged P-GEMM v2 (bf16 in/out): 128 rows/block ----------------
// W staged once per 128 rows; 2 row-tiles/wave; C bounced per-tile through 17.4KB LDS.
__global__ __launch_bounds__(256) void k_gemmP(
    const u16* __restrict__ S1, const u16* __restrict__ Wt1, u16* __restrict__ P1,
    int M1, int tiles1,
    const u16* __restrict__ S2, const u16* __restrict__ Wt2, u16* __restrict__ P2,
    int M2) {
  __shared__ __align__(16) u16 Wls[128 * 128];  // 32KB; Cls overlays first 17.4KB
  const u16* S; const u16* Wt; u16* P; int M, bm;
  if ((int)blockIdx.x < tiles1) { S = S1; Wt = Wt1; P = P1; M = M1; bm = blockIdx.x * 128; }
  else { S = S2; Wt = Wt2; P = P2; M = M2; bm = (blockIdx.x - tiles1) * 128; }
  const int tid = threadIdx.x, wv = tid >> 6, lane = tid & 63;
  const int lrow = lane & 15, quad = lane >> 4;
#pragma unroll
  for (int i = 0; i < 8; i++) {  // stage W swizzled
    int task = i * 256 + tid;
    int col = task >> 4, gr = task & 15;
    uint4 v = *(const uint4*)(Wt + (size_t)col * 128 + gr * 8);
    *(uint4*)(Wls + (size_t)col * 128 + ((gr ^ (col & 15)) * 8)) = v;
  }
  const bf16x8 zv = {0, 0, 0, 0, 0, 0, 0, 0};
  bf16x8 a[2][4];
#pragma unroll
  for (int tile = 0; tile < 2; tile++) {
    int arow = bm + tile * 64 + wv * 16 + lrow;
    bool arv = arow < M;
#pragma unroll
    for (int ks = 0; ks < 4; ks++)
      a[tile][ks] = arv ? *(const bf16x8*)(S + (size_t)arow * 128 + quad * 8 + ks * 32) : zv;
  }
  __syncthreads();
  floatx4 acc[2][8];
#pragma unroll
  for (int tile = 0; tile < 2; tile++)
#pragma unroll
    for (int ct = 0; ct < 8; ct++) acc[tile][ct] = {0.f, 0.f, 0.f, 0.f};
#pragma unroll
  for (int ks = 0; ks < 4; ks++) {
#pragma unroll
    for (int ct = 0; ct < 8; ct++) {
      int col = ct * 16 + lrow;
      bf16x8 b = *(const bf16x8*)(Wls + (size_t)col * 128 + (((4 * ks + quad) ^ lrow) * 8));
      acc[0][ct] = __builtin_amdgcn_mfma_f32_16x16x32_bf16(a[0][ks], b, acc[0][ct], 0, 0, 0);
      acc[1][ct] = __builtin_amdgcn_mfma_f32_16x16x32_bf16(a[1][ks], b, acc[1][ct], 0, 0, 0);
    }
  }
  u16* Cls = Wls;  // 64 x 136 bounce region
#pragma unroll
  for (int tile = 0; tile < 2; tile++) {
    __syncthreads();  // tile0: W reads done; tile1: prev write-out reads done
#pragma unroll
    for (int ct = 0; ct < 8; ct++) {
      int col = ct * 16 + lrow;
#pragma unroll
      for (int reg = 0; reg < 4; reg++) {
        int lr = wv * 16 + quad * 4 + reg;
        Cls[(size_t)lr * 136 + col] = f2bf(acc[tile][ct][reg]);
      }
    }
    __syncthreads();
#pragma unroll
    for (int i = 0; i < 4; i++) {  // coalesced bf16 write-out (64 rows)
      int task = i * 256 + tid;
      int row = task >> 4, c8 = task & 15;
      int gr2 = bm + tile * 64 + row;
      if (gr2 < M)
        *(uint4*)(P + (size_t)gr2 * 128 + c8 * 8) =
            *(const uint4*)(Cls + (size_t)row * 136 + c8 * 8);
    }
  }
}

// ---------------- fused message+GRU: Q-GEMM + gather-mean + GRU, per 64-node block ----------------
// round-13 structure + next-chunk weight prefetch into NAMED registers (no arrays ->
// no scratch; round-5's spill was the dynamically-indexed v[12] array).
__global__ __launch_bounds__(256, 3) void k_msggru(
    u16* __restrict__ st1, const u16* __restrict__ wq1, const float* __restrict__ qb1,
    const u16* __restrict__ P1g, const int* __restrict__ srcs1g,
    const int* __restrict__ off1g, const int* __restrict__ cnt1g,
    const u16* __restrict__ wx1, const u16* __restrict__ wh1, const float* __restrict__ gb1,
    int r1, int tiles1,
    u16* __restrict__ st2, const u16* __restrict__ wq2, const float* __restrict__ qb2,
    const u16* __restrict__ P2g, const int* __restrict__ srcs2g,
    const int* __restrict__ off2g, const int* __restrict__ cnt2g,
    const u16* __restrict__ wx2, const u16* __restrict__ wh2, const float* __restrict__ gb2,
    int r2) {
  __shared__ __align__(16) char smem[49152];
  __shared__ int offLs[64];
  __shared__ int cntLs[64];
  u16* Wq = (u16*)smem;                    // phase A: 128x128 bf16 swizzled (32KB)
  u16* Qb = (u16*)smem;                    // phase B: 64x128 bf16 (16KB)
  u16* Xb = (u16*)(smem + 16384);          // phase B: 64x128 bf16 swizzled (16KB)
  u16* Wg = (u16*)smem;                    // phase C: 6x16x128 bf16 swizzled (24KB)
  u16* Hls = (u16*)(smem + 32768);         // 64x128 bf16 swizzled (16KB), whole kernel
  u16* H; const u16* Wqb; const float* qbias; const u16* P;
  const int* srcs; const int* off; const int* cnt;
  const u16* Wxb; const u16* Whb; const float* gbias; int rows, bm;
  if ((int)blockIdx.x < tiles1) {
    H = st1; Wqb = wq1; qbias = qb1; P = P1g; srcs = srcs1g; off = off1g; cnt = cnt1g;
    Wxb = wx1; Whb = wh1; gbias = gb1; rows = r1; bm = blockIdx.x * 64;
  } else {
    H = st2; Wqb = wq2; qbias = qb2; P = P2g; srcs = srcs2g; off = off2g; cnt = cnt2g;
    Wxb = wx2; Whb = wh2; gbias = gb2; rows = r2; bm = (blockIdx.x - tiles1) * 64;
  }
  const int tid = threadIdx.x, wv = tid >> 6, lane = tid & 63;
  const int lrow = lane & 15, quad = lane >> 4;
  const uint4 z4 = {0, 0, 0, 0};
  // --- phase A: stage Wq (swizzled) + H (swizzled) + off/cnt ---
#pragma unroll
  for (int i = 0; i < 8; i++) {
    int task = i * 256 + tid;
    int col = task >> 4, gr = task & 15;
    uint4 v = *(const uint4*)(Wqb + (size_t)col * 128 + gr * 8);
    *(uint4*)(Wq + (size_t)col * 128 + ((gr ^ (col & 15)) * 8)) = v;
  }
#pragma unroll
  for (int i = 0; i < 4; i++) {
    int task = i * 256 + tid;
    int row = task >> 4, g = task & 15;
    int grow = bm + row;
    uint4 v = (grow < rows) ? *(const uint4*)(H + (size_t)grow * 128 + g * 8) : z4;
    *(uint4*)(Hls + (size_t)row * 128 + ((g ^ (row & 15)) * 8)) = v;
  }
  if (tid < 64) {
    int node = bm + tid;
    offLs[tid] = (node < rows) ? off[node] : 0;
    cntLs[tid] = (node < rows) ? cnt[node] : 0;
  }
  __syncthreads();
  // state A-frags (serve Q-GEMM and GRU h-GEMM)
  bf16x8 ah[4];
#pragma unroll
  for (int ks = 0; ks < 4; ks++)
    ah[ks] = *(const bf16x8*)(Hls + (size_t)(wv * 16 + lrow) * 128 + (((ks * 4 + quad) ^ lrow) * 8));
  // --- Q-GEMM: Q = state @ Wq^T ---
  floatx4 acc[8];
#pragma unroll
  for (int ct = 0; ct < 8; ct++) acc[ct] = {0.f, 0.f, 0.f, 0.f};
#pragma unroll
  for (int ks = 0; ks < 4; ks++) {
#pragma unroll
    for (int ct = 0; ct < 8; ct++) {
      int col = ct * 16 + lrow;
      bf16x8 b = *(const bf16x8*)(Wq + (size_t)col * 128 + (((4 * ks + quad) ^ lrow) * 8));
      acc[ct] = __builtin_amdgcn_mfma_f32_16x16x32_bf16(ah[ks], b, acc[ct], 0, 0, 0);
    }
  }
  __syncthreads();  // Wq reads done; region0 becomes Qb/Xb
  // --- write Q (+bias) as bf16, plain [row][col] ---
#pragma unroll
  for (int ct = 0; ct < 8; ct++) {
    int col = ct * 16 + lrow;
    float bv = qbias[col];
#pragma unroll
    for (int reg = 0; reg < 4; reg++) {
      int lr = wv * 16 + quad * 4 + reg;
      Qb[(size_t)lr * 128 + col] = f2bf(acc[ct][reg] + bv);
    }
  }
  __syncthreads();
  // --- gather-mean: X[node] = mean_e relu(P[src_e] + Q[node]) -> Xb (swizzled) ---
#pragma unroll
  for (int it = 0; it < 4; it++) {
    int task = it * 256 + tid;
    int nl = task >> 4, g = task & 15;
    int node = bm + nl;
    if (node >= rows) continue;
    int c8 = g << 3;
    float q[8];
    {
      uint4 qv = *(const uint4*)(Qb + (size_t)nl * 128 + c8);
      unsigned qq[4] = {qv.x, qv.y, qv.z, qv.w};
#pragma unroll
      for (int k = 0; k < 4; k++) {
        q[2 * k] = __uint_as_float(qq[k] << 16);
        q[2 * k + 1] = __uint_as_float(qq[k] & 0xffff0000u);
      }
    }
    float acg[8] = {0.f, 0.f, 0.f, 0.f, 0.f, 0.f, 0.f, 0.f};
    int o = offLs[nl], n = cntLs[nl];
    int i = 0;
    for (; i + 4 <= n; i += 4) {
      int s0 = srcs[o + i], s1 = srcs[o + i + 1], s2 = srcs[o + i + 2], s3 = srcs[o + i + 3];
      uint4 v0 = *(const uint4*)(P + (size_t)s0 * 128 + c8);
      uint4 v1 = *(const uint4*)(P + (size_t)s1 * 128 + c8);
      uint4 v2 = *(const uint4*)(P + (size_t)s2 * 128 + c8);
      uint4 v3 = *(const uint4*)(P + (size_t)s3 * 128 + c8);
      unsigned w[16] = {v0.x, v0.y, v0.z, v0.w, v1.x, v1.y, v1.z, v1.w,
                        v2.x, v2.y, v2.z, v2.w, v3.x, v3.y, v3.z, v3.w};
#pragma unroll
      for (int e = 0; e < 4; e++)
#pragma unroll
        for (int k = 0; k < 4; k++) {
          unsigned ww = w[e * 4 + k];
          float lo = __uint_as_float(ww << 16);
          float hi = __uint_as_float(ww & 0xffff0000u);
          acg[2 * k] += fmaxf(lo + q[2 * k], 0.f);
          acg[2 * k + 1] += fmaxf(hi + q[2 * k + 1], 0.f);
        }
    }
    for (; i < n; i++) {
      int s0 = srcs[o + i];
      uint4 v0 = *(const uint4*)(P + (size_t)s0 * 128 + c8);
      unsigned w[4] = {v0.x, v0.y, v0.z, v0.w};
#pragma unroll
      for (int k = 0; k < 4; k++) {
        unsigned ww = w[k];
        float lo = __uint_as_float(ww << 16);
        float hi = __uint_as_float(ww & 0xffff0000u);
        acg[2 * k] += fmaxf(lo + q[2 * k], 0.f);
        acg[2 * k + 1] += fmaxf(hi + q[2 * k + 1], 0.f);
      }
    }
    float inv = 1.f / fmaxf((float)n, 1.f);
    bf16x8 ov;
#pragma unroll
    for (int k = 0; k < 8; k++) ov[k] = (short)f2bf(acg[k] * inv);
    *(bf16x8*)(Xb + (size_t)nl * 128 + ((g ^ (nl & 15)) * 8)) = ov;
  }
  __syncthreads();
  // --- x A-frags from Xb ---
  bf16x8 ax[4];
#pragma unroll
  for (int ks = 0; ks < 4; ks++)
    ax[ks] = *(const bf16x8*)(Xb + (size_t)(wv * 16 + lrow) * 128 + (((ks * 4 + quad) ^ lrow) * 8));
  const int lr0 = wv * 16 + quad * 4;
  // --- per-thread staging pointers (6 tasks), then GRU chunk loop with prefetch ---
  const u16* gp0; const u16* gp1; const u16* gp2;
  const u16* gp3; const u16* gp4; const u16* gp5;
  u16* lp0; u16* lp1; u16* lp2; u16* lp3; u16* lp4; u16* lp5;
  {
#define MK_PTRS(J, GP, LP)                                                      \
    {                                                                           \
      int task = (J) * 256 + tid;                                               \
      int seg = task >> 8, rem = task & 255;                                    \
      int col = rem >> 4, gr = rem & 15;                                        \
      GP = (seg < 3 ? Wxb : Whb) +                                              \
           (size_t)((seg < 3 ? seg : seg - 3) * 128 + col) * 128 + gr * 8;      \
      LP = Wg + (size_t)(seg * 16 + col) * 128 + ((gr ^ col) * 8);              \
    }
    MK_PTRS(0, gp0, lp0) MK_PTRS(1, gp1, lp1) MK_PTRS(2, gp2, lp2)
    MK_PTRS(3, gp3, lp3) MK_PTRS(4, gp4, lp4) MK_PTRS(5, gp5, lp5)
#undef MK_PTRS
  }
  // preload chunk 0 (weights stride per chunk = 16 cols * 128 = 2048 u16)
  uint4 v0 = *(const uint4*)(gp0);
  uint4 v1 = *(const uint4*)(gp1);
  uint4 v2 = *(const uint4*)(gp2);
  uint4 v3 = *(const uint4*)(gp3);
  uint4 v4 = *(const uint4*)(gp4);
  uint4 v5 = *(const uint4*)(gp5);
  for (int ch = 0; ch < 8; ch++) {
    __syncthreads();  // ch=0: ax/Qb reads done; ch>0: prev Wg reads done
    *(uint4*)lp0 = v0; *(uint4*)lp1 = v1; *(uint4*)lp2 = v2;
    *(uint4*)lp3 = v3; *(uint4*)lp4 = v4; *(uint4*)lp5 = v5;
    __syncthreads();
    if (ch < 7) {  // prefetch next chunk; loads in flight across MFMA+epilogue
      size_t d = (size_t)(ch + 1) * 2048;
      v0 = *(const uint4*)(gp0 + d);
      v1 = *(const uint4*)(gp1 + d);
      v2 = *(const uint4*)(gp2 + d);
      v3 = *(const uint4*)(gp3 + d);
      v4 = *(const uint4*)(gp4 + d);
      v5 = *(const uint4*)(gp5 + d);
    }
    floatx4 gacc[3][2];
#pragma unroll
    for (int g = 0; g < 3; g++) {
      gacc[g][0] = {0.f, 0.f, 0.f, 0.f};
      gacc[g][1] = {0.f, 0.f, 0.f, 0.f};
    }
#pragma unroll
    for (int ks = 0; ks < 4; ks++) {
      int posu = ((4 * ks + quad) ^ lrow) * 8;
#pragma unroll
      for (int g = 0; g < 3; g++) {
        bf16x8 bx = *(const bf16x8*)(Wg + (size_t)(g * 16 + lrow) * 128 + posu);
        bf16x8 bh = *(const bf16x8*)(Wg + (size_t)((3 + g) * 16 + lrow) * 128 + posu);
        gacc[g][0] = __builtin_amdgcn_mfma_f32_16x16x32_bf16(ax[ks], bx, gacc[g][0], 0, 0, 0);
        gacc[g][1] = __builtin_amdgcn_mfma_f32_16x16x32_bf16(ah[ks], bh, gacc[g][1], 0, 0, 0);
      }
    }
    int hcol = ch * 16 + lrow;
    float bxz = gbias[hcol];
    float bxr = gbias[128 + hcol];
    float bxh = gbias[256 + hcol];
    float bhz = gbias[384 + hcol];
    float bhr = gbias[384 + 128 + hcol];
    float bhh = gbias[384 + 256 + hcol];
    int ggr = 2 * ch + (lrow >> 3);
    int gel = lrow & 7;
#pragma unroll
    for (int reg = 0; reg < 4; reg++) {
      int lr = lr0 + reg;
      float xz = gacc[0][0][reg] + bxz;
      float xr = gacc[1][0][reg] + bxr;
      float xh = gacc[2][0][reg] + bxh;
      float hz = gacc[0][1][reg] + bhz;
      float hr = gacc[1][1][reg] + bhr;
      float hh = gacc[2][1][reg] + bhh;
      float z = fsigmoid(xz + hz);
      float rr = fsigmoid(xr + hr);
      float hc = ftanh(xh + rr * hh);
      u16* hp = Hls + (size_t)lr * 128 + ((ggr ^ (lr & 15)) * 8) + gel;
      float hold = bf2f(*hp);
      *hp = f2bf(z * hold + (1.f - z) * hc);
    }
  }
  __syncthreads();
  // --- coalesced state write-out ---
#pragma unroll
  for (int i = 0; i < 4; i++) {
    int task = i * 256 + tid;
    int row = task >> 4, g = task & 15;
    int grow = bm + row;
    if (grow < rows)
      *(uint4*)(H + (size_t)grow * 128 + g * 8) =
          *(const uint4*)(Hls + (size_t)row * 128 + ((g ^ (row & 15)) * 8));
  }
}

// ---------------- fully fused readout: 2 GEMMs + logits + softmax ----------------
__global__ __launch_bounds__(256) void k_readout2(
    const u16* __restrict__ S, const u16* __restrict__ W1b, const float* __restrict__ b1,
    const u16* __restrict__ W2b, const float* __restrict__ b2,
    const float* __restrict__ W3, const float* __restrict__ b3,
    float* __restrict__ out, int M) {
  __shared__ __align__(16) char smem[64 * 132 * 4];  // 33792 B
  u16* Wls = (u16*)smem;
  u16* H1ls = (u16*)smem;
  u16* W2ls = (u16*)(smem + 17408);
  u16* H2ls = (u16*)smem;
  float* W3ls = (float*)(smem + 9216);
  float* b3ls = (float*)(smem + 9216 + 3840);
  const int tid = threadIdx.x, wv = tid >> 6, lane = tid & 63;
  const int lrow = lane & 15, quad = lane >> 4;
  const int bm = blockIdx.x * 64;
#pragma unroll
  for (int i = 0; i < 8; i++) {
    int task = i * 256 + tid;
    int col = task >> 4, gr = task & 15;
    uint4 v = *(const uint4*)(W1b + (size_t)col * 128 + gr * 8);
    *(uint4*)(Wls + (size_t)col * 128 + ((gr ^ (col & 15)) * 8)) = v;
  }
  const int arow = bm + wv * 16 + lrow;
  const bool arv = arow < M;
  const bf16x8 zv = {0, 0, 0, 0, 0, 0, 0, 0};
  bf16x8 a[4];
#pragma unroll
  for (int ks = 0; ks < 4; ks++)
    a[ks] = arv ? *(const bf16x8*)(S + (size_t)arow * 128 + quad * 8 + ks * 32) : zv;
  __syncthreads();
  floatx4 acc1[8];
#pragma unroll
  for (int ct = 0; ct < 8; ct++) acc1[ct] = {0.f, 0.f, 0.f, 0.f};
#pragma unroll
  for (int ks = 0; ks < 4; ks++) {
#pragma unroll
    for (int ct = 0; ct < 8; ct++) {
      int col = ct * 16 + lrow;
      bf16x8 b = *(const bf16x8*)(Wls + (size_t)col * 128 + (((4 * ks + quad) ^ lrow) * 8));
      acc1[ct] = __builtin_amdgcn_mfma_f32_16x16x32_bf16(a[ks], b, acc1[ct], 0, 0, 0);
    }
  }
  __syncthreads();
#pragma unroll
  for (int ct = 0; ct < 8; ct++) {
    int col = ct * 16 + lrow;
    float bv = b1[col];
#pragma unroll
    for (int reg = 0; reg < 4; reg++) {
      int lr = wv * 16 + quad * 4 + reg;
      H1ls[(size_t)lr * 136 + col] = f2bf(fmaxf(acc1[ct][reg] + bv, 0.f));
    }
  }
#pragma unroll
  for (int i = 0; i < 4; i++) {
    int task = i * 256 + tid;
    int col = task >> 4, gr = task & 15;
    uint4 v = *(const uint4*)(W2b + (size_t)col * 128 + gr * 8);
    *(uint4*)(W2ls + (size_t)col * 128 + ((gr ^ (col & 15)) * 8)) = v;
  }
  __syncthreads();
  bf16x8 a2[4];
#pragma unroll
  for (int ks = 0; ks < 4; ks++)
    a2[ks] = *(const bf16x8*)(H1ls + (size_t)(wv * 16 + lrow) * 136 + quad * 8 + ks * 32);
  floatx4 acc2[4];
#pragma unroll
  for (int ct = 0; ct < 4; ct++) acc2[ct] = {0.f, 0.f, 0.f, 0.f};
#pragma unroll
  for (int ks = 0; ks < 4; ks++) {
#pragma unroll
    for (int ct = 0; ct < 4; ct++) {
      int col = ct * 16 + lrow;
      bf16x8 b = *(const bf16x8*)(W2ls + (size_t)col * 128 + (((4 * ks + quad) ^ lrow) * 8));
      acc2[ct] = __builtin_amdgcn_mfma_f32_16x16x32_bf16(a2[ks], b, acc2[ct], 0, 0, 0);
    }
  }
  __syncthreads();
#pragma unroll
  for (int ct = 0; ct < 4; ct++) {
    int col = ct * 16 + lrow;
    float bv = b2[col];
#pragma unroll
    for (int reg = 0; reg < 4; reg++) {
      int lr = wv * 16 + quad * 4 + reg;
      H2ls[(size_t)lr * 72 + col] = f2bf(fmaxf(acc2[ct][reg] + bv, 0.f));
    }
  }
  for (int l = tid; l < 960; l += 256) W3ls[l] = W3[l];
  if (tid < 15) b3ls[tid] = b3[tid];
  __syncthreads();
  if (tid < 64) {
    int row = tid, gr2 = bm + row;
    if (gr2 < M) {
      float lg[15];
#pragma unroll
      for (int c = 0; c < 15; c++) lg[c] = b3ls[c];
      for (int k = 0; k < 64; k++) {
        float hk = bf2f(H2ls[(size_t)row * 72 + k]);
#pragma unroll
        for (int c = 0; c < 15; c++) lg[c] += hk * W3ls[k * 15 + c];
      }
      float m = lg[0];
#pragma unroll
      for (int c = 1; c < 15; c++) m = fmaxf(m, lg[c]);
      float ssum = 0.f;
#pragma unroll
      for (int c = 0; c < 15; c++) { lg[c] = __expf(lg[c] - m); ssum += lg[c]; }
      float inv = 1.f / ssum;
#pragma unroll
      for (int c = 0; c < 15; c++) out[(size_t)gr2 * 15 + c] = lg[c] * inv;
    }
  }
}

// ---------------- launch ----------------
extern "C" void kernel_launch(void* const* d_in, const int* in_sizes, int n_in,
                              void* d_out, int out_size, void* d_ws, size_t ws_size,
                              hipStream_t stream) {
  const float* feat = (const float*)d_in[0];
  const int* src1 = (const int*)d_in[1];
  const int* dst1 = (const int*)d_in[2];
  const int* src2 = (const int*)d_in[3];
  const int* dst2 = (const int*)d_in[4];
  const float* Wm1 = (const float*)d_in[5];
  const float* bm1 = (const float*)d_in[6];
  const float* Wm2 = (const float*)d_in[7];
  const float* bm2 = (const float*)d_in[8];
  const float* gik = (const float*)d_in[9];
  const float* gir = (const float*)d_in[10];
  const float* gib = (const float*)d_in[11];
  const float* gck = (const float*)d_in[12];
  const float* gcr = (const float*)d_in[13];
  const float* gcb = (const float*)d_in[14];
  const float* Wr1 = (const float*)d_in[15];
  const float* br1 = (const float*)d_in[16];
  const float* Wr2 = (const float*)d_in[17];
  const float* br2 = (const float*)d_in[18];
  const float* Wr3 = (const float*)d_in[19];
  const float* br3 = (const float*)d_in[20];
  float* out = (float*)d_out;

  // ---- workspace layout (u16 units) ----
  u16* w16 = (u16*)d_ws;
  size_t o = 0;
  u16* ip_state = w16 + o;   o += (size_t)N_IP * D;
  u16* conn_state = w16 + o; o += (size_t)N_CONN * D;
  u16* P1 = w16 + o;         o += (size_t)N_IP * D;
  u16* P2 = w16 + o;         o += (size_t)N_CONN * D;
  u16* gikb = w16 + o;       o += 49152;
  u16* girb = w16 + o;       o += 49152;
  u16* gckb = w16 + o;       o += 49152;
  u16* gcrb = w16 + o;       o += 49152;
  u16* wm1b = w16 + o;       o += 16384;
  u16* wm2b = w16 + o;       o += 16384;
  u16* wm1t = w16 + o;       o += 16384;
  u16* wm2t = w16 + o;       o += 16384;
  u16* wr1b = w16 + o;       o += 16384;
  u16* wr2b = w16 + o;       o += 8192;
  int* ip = (int*)(w16 + o);
  int* cnt1 = ip;  ip += N_CONN;
  int* cnt2 = ip;  ip += N_IP;
  int* off1 = ip;  ip += N_CONN;
  int* off2 = ip;  ip += N_IP;
  int* cur1 = ip;  ip += N_CONN;
  int* cur2 = ip;  ip += N_IP;
  int* srcs1 = ip; ip += NE;
  int* srcs2 = ip; ip += NE;
  int* bsum1 = ip; ip += 256;
  int* bsum2 = ip; ip += 256;

  const int BT = 256;

  // ---- fused init + weight prep ----
  const int nstate = (N_IP + N_CONN) * D;
  k_init_all<<<(nstate + BT - 1) / BT, BT, 0, stream>>>(ip_state, conn_state, feat, cnt1);
  k_prep_all<<<(286720 + BT - 1) / BT, BT, 0, stream>>>(
      gik, gir, gck, gcr, Wm1, Wm2, Wr1, Wr2,
      gikb, girb, gckb, gcrb, wm1b, wm2b, wm1t, wm2t, wr1b, wr2b);

  // ---- build CSR ----
  k_count<<<(NE + BT - 1) / BT, BT, 0, stream>>>(dst1, dst2, cnt1, cnt2);
  const int nb1 = (N_CONN + 1023) / 1024, nb2 = (N_IP + 1023) / 1024;
  k_scan_part2<<<nb1 + nb2, 256, 0, stream>>>(cnt1, bsum1, N_CONN, nb1, cnt2, bsum2, N_IP);
  k_scan_mid2<<<1, 256, 0, stream>>>(bsum1, nb1, bsum2, nb2);
  k_scan_final2<<<nb1 + nb2, 256, 0, stream>>>(cnt1, bsum1, off1, cur1, N_CONN, nb1,
                                               cnt2, bsum2, off2, cur2, N_IP);
  k_scatter<<<(NE + BT - 1) / BT, BT, 0, stream>>>(src1, dst1, src2, dst2,
                                                   cur1, cur2, srcs1, srcs2);

  const int t64ip = (N_IP + 63) / 64;       // 313
  const int t64cn = (N_CONN + 63) / 64;     // 1563
  const int t128ip = (N_IP + 127) / 128;    // 157
  const int t128cn = (N_CONN + 127) / 128;  // 782

  for (int t = 0; t < T_ROUNDS; t++) {
    // P1 = old ip_state @ Wm1_top; P2 = old conn_state @ Wm2_top
    k_gemmP<<<t128ip + t128cn, 256, 0, stream>>>(ip_state, wm1t, P1, N_IP, t128ip,
                                                 conn_state, wm2t, P2, N_CONN);
    // fused Q-GEMM + gather-mean + GRU for both node types
    k_msggru<<<t64cn + t64ip, 256, 0, stream>>>(
        conn_state, wm1b, bm1, P1, srcs1, off1, cnt1, gckb, gcrb, gcb, N_CONN, t64cn,
        ip_state, wm2b, bm2, P2, srcs2, off2, cnt2, gikb, girb, gib, N_IP);
  }

  k_readout2<<<t64cn, 256, 0, stream>>>(conn_state, wr1b, br1, wr2b, br2,
                                        Wr3, br3, out, N_CONN);
}